// Round 17
// baseline (169.592 us; speedup 1.0000x reference)
//
#include <hip/hip_runtime.h>

// Attention_29231547416680: B=4, N=2048, CH=512, H=8, D=64, fp32 in/out.
// R17 = R16 with attn cross-iteration pipeline (T15): QK^T(i+1) issued
//       alongside softmax(i) so MFMA overlaps the serial VALU chain; two
//       s-register sets (even/odd manual unroll), 2 barriers/iter.
//       prep/proj byte-identical to R16.

typedef float f32x4 __attribute__((ext_vector_type(4)));
typedef float f32x16 __attribute__((ext_vector_type(16)));
typedef short short8 __attribute__((ext_vector_type(8)));

#define MFMA16(a, b, c) __builtin_amdgcn_mfma_f32_16x16x32_bf16((a), (b), (c), 0, 0, 0)
#define MFMA32(a, b, c) __builtin_amdgcn_mfma_f32_32x32x16_bf16((a), (b), (c), 0, 0, 0)

#if __has_builtin(__builtin_amdgcn_exp2f)
#define EXP2(x) __builtin_amdgcn_exp2f(x)
#else
#define EXP2(x) exp2f(x)
#endif

#define NBH 32
#define NSEQ 2048
#define DH 64

__device__ __forceinline__ unsigned short f2bf(float f) {
  unsigned int u = __float_as_uint(f);
  u += 0x7fffu + ((u >> 16) & 1u);  // RTNE
  return (unsigned short)(u >> 16);
}
__device__ __forceinline__ float bf2f(unsigned short h) {
  return __uint_as_float(((unsigned int)h) << 16);
}
__device__ __forceinline__ void split_bf16(float f, unsigned short& hi, unsigned short& lo) {
  hi = f2bf(f);
  lo = f2bf(f - bf2f(hi));
}

__device__ __forceinline__ unsigned cvtpk_bf16(float a, float b) {
  unsigned d;
  asm("v_cvt_pk_bf16_f32 %0, %1, %2" : "=v"(d) : "v"(a), "v"(b));
  return d;
}
__device__ __forceinline__ void permswap(unsigned& a, unsigned& b) {
  asm("v_permlane32_swap_b32 %0, %1" : "+v"(a), "+v"(b));
}
// lo = (ce.row0 | co.row0), hi = (ce.row1 | co.row1); S2 selects HW direction.
template <bool S2>
__device__ __forceinline__ void xsw(unsigned ce, unsigned co, unsigned& lo, unsigned& hi) {
  if (S2) { permswap(ce, co); }
  else    { permswap(co, ce); }
  lo = ce;
  hi = co;
}

// async global -> LDS, 16 bytes per lane; LDS dst = wave-uniform base + lane*16.
typedef __attribute__((address_space(1))) const unsigned int as1_u32;
typedef __attribute__((address_space(3))) unsigned int as3_u32;
__device__ __forceinline__ void gld_lds16(const unsigned short* g, unsigned short* l) {
  __builtin_amdgcn_global_load_lds((as1_u32*)g, (as3_u32*)l, 16, 0, 0);
}

// ---------------- prep: mask bit-pack + x/W hi-lo split (R16 verbatim) ----------------
__global__ __launch_bounds__(256) void prep_kernel(
    const void* __restrict__ mraw, unsigned long long* __restrict__ Mp,
    const float* __restrict__ x,
    const float* __restrict__ Wq, const float* __restrict__ Wk, const float* __restrict__ Wv,
    unsigned short* __restrict__ xh, unsigned short* __restrict__ xl,
    unsigned short* __restrict__ wh, unsigned short* __restrict__ wl) {
  const int tid = threadIdx.x;
  __shared__ int s_bad;
  if (tid == 0) s_bad = 0;
  __syncthreads();
  const unsigned int* mw32 = (const unsigned int*)mraw;
  {
    unsigned int w0 = mw32[tid], w1 = mw32[256 + tid];
    bool ok = (w0 == 0u || w0 == 1u || w0 == 0x3f800000u) &&
              (w1 == 0u || w1 == 1u || w1 == 0x3f800000u);
    if (!ok) s_bad = 1;
  }
  __syncthreads();
  const size_t e0 = (size_t)blockIdx.x * 16384 + (size_t)tid * 64;
  unsigned long long bits = 0ull;
  if (s_bad == 0) {
    const uint4* p = (const uint4*)mw32 + (e0 >> 2);
#pragma unroll
    for (int j = 0; j < 16; ++j) {
      uint4 v = p[j];
      unsigned nib = (v.x != 0u) | ((v.y != 0u) << 1) | ((v.z != 0u) << 2) | ((v.w != 0u) << 3);
      bits |= (unsigned long long)nib << (j * 4);
    }
  } else {
    const uint4* p = (const uint4*)((const unsigned char*)mraw + e0);
#pragma unroll
    for (int j = 0; j < 4; ++j) {
      uint4 v = p[j];
      unsigned dw[4] = {v.x, v.y, v.z, v.w};
#pragma unroll
      for (int d = 0; d < 4; ++d) {
        unsigned nib = (((dw[d]) & 0xffu) != 0u) | ((((dw[d] >> 8) & 0xffu) != 0u) << 1) |
                       ((((dw[d] >> 16) & 0xffu) != 0u) << 2) | ((((dw[d] >> 24) & 0xffu) != 0u) << 3);
        bits |= (unsigned long long)nib << ((j * 4 + d) * 4);
      }
    }
  }
  Mp[e0 >> 6] = bits;

  const int gtid = blockIdx.x * 256 + tid;
  const float4* x4 = (const float4*)x;
#pragma unroll
  for (int rep = 0; rep < 4; ++rep) {
    int i = gtid + rep * 262144;
    float4 v = x4[i];
    unsigned short h0, l0, h1, l1, h2, l2, h3, l3;
    split_bf16(v.x, h0, l0); split_bf16(v.y, h1, l1);
    split_bf16(v.z, h2, l2); split_bf16(v.w, h3, l3);
    *(ushort4*)&xh[(size_t)i * 4] = make_ushort4(h0, h1, h2, h3);
    *(ushort4*)&xl[(size_t)i * 4] = make_ushort4(l0, l1, l2, l3);
  }
  if (gtid < 65536) {
    const float* Ws[3] = {Wq, Wk, Wv};
#pragma unroll
    for (int z = 0; z < 3; ++z) {
      float4 v = ((const float4*)Ws[z])[gtid];
      unsigned short h0, l0, h1, l1, h2, l2, h3, l3;
      split_bf16(v.x, h0, l0); split_bf16(v.y, h1, l1);
      split_bf16(v.z, h2, l2); split_bf16(v.w, h3, l3);
      size_t o = (size_t)z * 262144 + (size_t)gtid * 4;
      *(ushort4*)&wh[o] = make_ushort4(h0, h1, h2, h3);
      *(ushort4*)&wl[o] = make_ushort4(l0, l1, l2, l3);
    }
  }
}

// ---------------- Kernel 1: QKV projection (R16 verbatim) ----------------
__global__ __launch_bounds__(256, 4) void proj_kernel(
    const unsigned short* __restrict__ xh, const unsigned short* __restrict__ xl,
    const unsigned short* __restrict__ wh, const unsigned short* __restrict__ wl,
    unsigned short* __restrict__ Qh, unsigned short* __restrict__ Kh,
    unsigned short* __restrict__ Vh) {
  const int tid = threadIdx.x;
  const int w = tid >> 6, l = tid & 63;
  const int m0 = blockIdx.x * 64;
  const int h = blockIdx.y;
  const int lrow = l & 15, lg = l >> 4;
  const int rw = (w >> 1) * 32, cw = (w & 1) * 32;

  union LDSU {
    unsigned short tiles[8][64][32];  // 32 KB staging
    unsigned short ob[64][72];        // epilogue bounce
  };
  __shared__ __align__(16) LDSU u;

  f32x4 acc[3][2][2] = {};

  const unsigned short* planes[8] = {xh, xl, wh, wl, wh + 262144, wl + 262144,
                                     wh + 524288, wl + 524288};
  const int rowb[8] = {m0, m0, h * 64, h * 64, h * 64, h * 64, h * 64, h * 64};
  const int srow = l >> 2, scol = (l & 3) * 8;
  const unsigned short* s0 = planes[2 * w] + (size_t)(rowb[2 * w] + srow) * 512 + scol;
  const unsigned short* s1 = planes[2 * w + 1] + (size_t)(rowb[2 * w + 1] + srow) * 512 + scol;
  unsigned short* d0 = &u.tiles[2 * w][0][0];
  unsigned short* d1 = &u.tiles[2 * w + 1][0][0];

  for (int k0 = 0; k0 < 512; k0 += 32) {
    __syncthreads();
#pragma unroll
    for (int c = 0; c < 4; ++c) {
      gld_lds16(s0 + k0 + c * 8192, d0 + c * 512);
      gld_lds16(s1 + k0 + c * 8192, d1 + c * 512);
    }
    __syncthreads();

    short8 axh[2], axl[2];
#pragma unroll
    for (int t = 0; t < 2; ++t) {
      axh[t] = *(const short8*)&u.tiles[0][rw + 16 * t + lrow][lg * 8];
      axl[t] = *(const short8*)&u.tiles[1][rw + 16 * t + lrow][lg * 8];
    }
#pragma unroll
    for (int z = 0; z < 3; ++z) {
      short8 bh[2], bl[2];
#pragma unroll
      for (int t = 0; t < 2; ++t) {
        bh[t] = *(const short8*)&u.tiles[2 + 2 * z][cw + 16 * t + lrow][lg * 8];
        bl[t] = *(const short8*)&u.tiles[3 + 2 * z][cw + 16 * t + lrow][lg * 8];
      }
#pragma unroll
      for (int tm = 0; tm < 2; ++tm)
#pragma unroll
        for (int tn = 0; tn < 2; ++tn) {
          acc[z][tm][tn] = MFMA16(axh[tm], bh[tn], acc[z][tm][tn]);
          acc[z][tm][tn] = MFMA16(axh[tm], bl[tn], acc[z][tm][tn]);
          acc[z][tm][tn] = MFMA16(axl[tm], bh[tn], acc[z][tm][tn]);
        }
    }
  }

  const float qsc = 1.4426950408889634f * 0.08838834764831845f;  // log2e/sqrt(128)
  const int orow = tid >> 2, oc = (tid & 3) * 16;
  const int b = m0 >> 11, n0 = m0 & 2047, bhid = b * 8 + h;
#pragma unroll
  for (int z = 0; z < 3; ++z) {
    __syncthreads();
#pragma unroll
    for (int tm = 0; tm < 2; ++tm)
#pragma unroll
      for (int tn = 0; tn < 2; ++tn) {
        int dcol = cw + tn * 16 + lrow;
        int nl = rw + tm * 16 + lg * 4;
#pragma unroll
        for (int r = 0; r < 4; ++r) {
          float v = acc[z][tm][tn][r];
          if (z == 0) v *= qsc;
          if (z < 2) u.ob[nl + r][dcol] = f2bf(v);
          else       u.ob[dcol][nl + r] = f2bf(v);  // V: transposed
        }
      }
    __syncthreads();
    if (z < 2) {
      unsigned short* O = (z == 0) ? Qh : Kh;
      size_t base = ((size_t)bhid * 2048 + n0 + orow) * 64 + oc;
      *(short8*)&O[base] = *(const short8*)&u.ob[orow][oc];
      *(short8*)&O[base + 8] = *(const short8*)&u.ob[orow][oc + 8];
    } else {
      size_t vb = ((size_t)bhid * 64 + orow) * 2048 + n0 + oc;
      *(short8*)&Vh[vb] = *(const short8*)&u.ob[orow][oc];
      *(short8*)&Vh[vb + 8] = *(const short8*)&u.ob[orow][oc + 8];
    }
  }
}

// ---------------- attention body (cross-iteration pipeline) ----------------
template <bool S2>
__device__ __forceinline__ void attn_body(
    unsigned short (&kvb)[2][4][64][64],
    const unsigned short* __restrict__ Qh,
    const unsigned short* __restrict__ Kh, const unsigned short* __restrict__ Vh,
    const unsigned long long* __restrict__ Mp, float* __restrict__ out) {
  const int tid = threadIdx.x;
  const int w = tid >> 6, l = tid & 63;
  const int wl = blockIdx.x;
  const int rm = (wl & 7) * 64 + (wl >> 3);  // XCD swizzle (512 = 8*64, bijective)
  const int q0 = (rm & 15) * 128;
  const int bh = rm >> 4;
  const int b = bh >> 3, h = bh & 7;
  const int l31 = l & 31, hi = l >> 5;
  const int swz = (l31 & 7) << 4;

  const unsigned short* Qhb = Qh + (size_t)bh * NSEQ * DH;
  const unsigned short* Khb = Kh + (size_t)bh * NSEQ * DH;
  const unsigned short* Vhb = Vh + (size_t)bh * DH * NSEQ;
  const unsigned long long* Mb = Mp + (size_t)b * NSEQ * 32;
  float* Ob = out + (size_t)b * NSEQ * 512 + h * 64;

  // buffer = 4 sub-planes x 8KB: Ka(0) Kb(8192) Va(16384) Vb(24576); dbuf stride 32768.
  char* kv0 = (char*)&kvb[0][0][0][0];

  int va[4];
#pragma unroll
  for (int d = 0; d < 4; ++d) va[d] = l31 * 128 + (((d * 32) | (hi * 16)) ^ swz);

  const size_t qoff = (size_t)(q0 + w * 32 + l31) * 64 + hi * 8;
  short8 qh[4];
#pragma unroll
  for (int d = 0; d < 4; ++d) qh[d] = *(const short8*)(Qhb + qoff + d * 16);

  short8 ones;
#pragma unroll
  for (int j = 0; j < 8; ++j) ones[j] = (short)0x3F80;

  f32x16 o[2] = {};
  f32x16 osum = {};  // element 0 = running row-sum l
  float mrun = -1e30f;
  const int qglob = q0 + w * 32 + l31;

  // staging: 256 threads x 4 K-chunks + 4 V-chunks of short8
  const int row0 = tid >> 3, colx = (tid & 7) * 8;
  const int swst = (colx * 2) ^ ((row0 & 7) << 4);
  int dstK[4], dstV[4];
#pragma unroll
  for (int c = 0; c < 4; ++c) {
    const int rsub = (c & 1) * 32 + row0;
    dstK[c] = (c >> 1) * 8192 + rsub * 128 + swst;
    dstV[c] = 16384 + (c >> 1) * 8192 + rsub * 128 + swst;
  }
  size_t koff[4], voff[4];
#pragma unroll
  for (int c = 0; c < 4; ++c) {
    koff[c] = (size_t)(c * 32 + row0) * 64 + colx;
    voff[c] = (size_t)((c & 1) * 32 + row0) * 2048 + (c >> 1) * 64 + colx;
  }

  short8 sk[4], sv[4];
  // ---- prologue ----
#pragma unroll
  for (int c = 0; c < 4; ++c) {           // tile 0 -> regs
    sk[c] = *(const short8*)(Khb + koff[c]);
    sv[c] = *(const short8*)(Vhb + voff[c]);
  }
#pragma unroll
  for (int c = 0; c < 4; ++c) {           // regs -> buf0
    *(short8*)(kv0 + dstK[c]) = sk[c];
    *(short8*)(kv0 + dstV[c]) = sv[c];
  }
#pragma unroll
  for (int c = 0; c < 4; ++c) {           // tile 1 -> regs
    koff[c] += 8192; voff[c] += 128;
    sk[c] = *(const short8*)(Khb + koff[c]);
    sv[c] = *(const short8*)(Vhb + voff[c]);
  }
  __syncthreads();                        // buf0 visible

  f32x16 sE[2] = {}, sO[2] = {};
  // QK^T(0) from buf0 -> sE
  __builtin_amdgcn_s_setprio(1);
#pragma unroll
  for (int d = 0; d < 4; ++d) {
#pragma unroll
    for (int kt = 0; kt < 2; ++kt) {
      short8 kfa = *(const short8*)(kv0 + kt * 4096 + va[d]);
      short8 kfb = *(const short8*)(kv0 + 8192 + kt * 4096 + va[d]);
      sE[0 + 0] = (kt == 0 && d == -1) ? sE[0] : sE[0];  // no-op keep structure
      sE[kt] = MFMA32(kfa, qh[d], sE[kt]);
      sO[kt] = sO[kt];  // placeholder removed below
      sE[kt] = sE[kt];
      // tile B accumulates into the second half of the pair: use separate regs
      // (handled by sB below)
      (void)kfb;
    }
  }
  __builtin_amdgcn_s_setprio(0);
  // NOTE: sE holds tile-A S; tile-B S needs its own pair. Use 4-vector sets:
  // Redo cleanly: sE = {A0,A1}, sEb = {B0,B1} etc.
  f32x16 sEb[2] = {}, sOb[2] = {};
  {
    // recompute tile-B for tile 0 (kept separate for clarity; MFMAs above only did A)
    __builtin_amdgcn_s_setprio(1);
#pragma unroll
    for (int d = 0; d < 4; ++d) {
#pragma unroll
      for (int kt = 0; kt < 2; ++kt) {
        short8 kfb = *(const short8*)(kv0 + 8192 + kt * 4096 + va[d]);
        sEb[kt] = MFMA32(kfb, qh[d], sEb[kt]);
      }
    }
    __builtin_amdgcn_s_setprio(0);
  }
#pragma unroll
  for (int c = 0; c < 4; ++c) {           // regs(tile1) -> buf1
    *(short8*)(kv0 + 32768 + dstK[c]) = sk[c];
    *(short8*)(kv0 + 32768 + dstV[c]) = sv[c];
  }
#pragma unroll
  for (int c = 0; c < 4; ++c) {           // tile 2 -> regs
    koff[c] += 8192; voff[c] += 128;
    sk[c] = *(const short8*)(Khb + koff[c]);
    sv[c] = *(const short8*)(Vhb + voff[c]);
  }
  __syncthreads();                        // buf1 visible

  // half-iteration body
  auto half = [&](int it, f32x16 (&sA)[2], f32x16 (&sB)[2],
                  f32x16 (&nA)[2], f32x16 (&nB)[2], int curOff, int nxtOff) {
    // mask words for current tile pair (issue early)
    const unsigned long long mwA = Mb[(size_t)qglob * 32 + 2 * it];
    const unsigned long long mwB = Mb[(size_t)qglob * 32 + 2 * it + 1];

    // ---- QK^T(it+1) into nA/nB (overlaps softmax below) ----
    if (it < 15) {
#pragma unroll
      for (int kt = 0; kt < 2; ++kt) { nA[kt] = (f32x16){}; nB[kt] = (f32x16){}; }
#pragma unroll
      for (int d = 0; d < 4; ++d) {
#pragma unroll
        for (int kt = 0; kt < 2; ++kt) {
          short8 kfa = *(const short8*)(kv0 + nxtOff + kt * 4096 + va[d]);
          short8 kfb = *(const short8*)(kv0 + nxtOff + 8192 + kt * 4096 + va[d]);
          nA[kt] = MFMA32(kfa, qh[d], nA[kt]);
          nB[kt] = MFMA32(kfb, qh[d], nB[kt]);
        }
      }
    }

    // ---- softmax(it) on sA/sB ----
#pragma unroll
    for (int kt = 0; kt < 2; ++kt)
#pragma unroll
      for (int m = 0; m < 4; ++m) {
        unsigned nibA = ((unsigned)(mwA >> (kt * 32 + m * 8 + 4 * hi))) & 0xFu;
        unsigned nibB = ((unsigned)(mwB >> (kt * 32 + m * 8 + 4 * hi))) & 0xFu;
#pragma unroll
        for (int r = 0; r < 4; ++r) {
          sA[kt][4 * m + r] = ((nibA >> r) & 1u) ? -1e30f : sA[kt][4 * m + r];
          sB[kt][4 * m + r] = ((nibB >> r) & 1u) ? -1e30f : sB[kt][4 * m + r];
        }
      }
    float mx = fmaxf(sA[0][0], sB[0][0]);
#pragma unroll
    for (int kt = 0; kt < 2; ++kt)
#pragma unroll
      for (int e = (kt == 0 ? 1 : 0); e < 16; ++e)
        mx = fmaxf(fmaxf(sA[kt][e], sB[kt][e]), mx);
    mx = fmaxf(mx, __shfl_xor(mx, 32));
    const bool grow = __any(mx > mrun + 11.0f);
    const float mnew = grow ? fmaxf(mrun, mx) : mrun;

#pragma unroll
    for (int kt = 0; kt < 2; ++kt)
#pragma unroll
      for (int e = 0; e < 16; ++e) {
        sA[kt][e] = EXP2(sA[kt][e] - mnew);
        sB[kt][e] = EXP2(sB[kt][e] - mnew);
      }
    if (grow) {
      float sc = EXP2(mrun - mnew);
      mrun = mnew;
      osum[0] *= sc;
#pragma unroll
      for (int dt = 0; dt < 2; ++dt)
#pragma unroll
        for (int e = 0; e < 16; ++e) o[dt][e] *= sc;
    }

    // ---- tile A: frags + PV ----
    {
      short8 fragh[4];
#pragma unroll
      for (int kt = 0; kt < 2; ++kt) {
        unsigned c0h[4], c1h[4];
#pragma unroll
        for (int m = 0; m < 4; ++m) {
          c0h[m] = cvtpk_bf16(sA[kt][4 * m + 0], sA[kt][4 * m + 1]);
          c1h[m] = cvtpk_bf16(sA[kt][4 * m + 2], sA[kt][4 * m + 3]);
        }
#pragma unroll
        for (int sI = 0; sI < 2; ++sI) {
          unsigned dw0, dw1, dw2, dw3;
          xsw<S2>(c0h[2 * sI], c0h[2 * sI + 1], dw0, dw2);
          xsw<S2>(c1h[2 * sI], c1h[2 * sI + 1], dw1, dw3);
          union U { uint4 u; short8 s8; } FH;
          FH.u = make_uint4(dw0, dw1, dw2, dw3);
          fragh[kt * 2 + sI] = FH.s8;
        }
      }
      __builtin_amdgcn_s_setprio(1);
#pragma unroll
      for (int ks = 0; ks < 4; ++ks) {
        short8 vf0 = *(const short8*)(kv0 + curOff + 16384 + va[ks]);
        short8 vf1 = *(const short8*)(kv0 + curOff + 16384 + 4096 + va[ks]);
        o[0] = MFMA32(vf0, fragh[ks], o[0]);
        o[1] = MFMA32(vf1, fragh[ks], o[1]);
        osum = MFMA32(ones, fragh[ks], osum);
      }
      __builtin_amdgcn_s_setprio(0);
    }
    // ---- tile B: frags + PV ----
    {
      short8 fragh[4];
#pragma unroll
      for (int kt = 0; kt < 2; ++kt) {
        unsigned c0h[4], c1h[4];
#pragma unroll
        for (int m = 0; m < 4; ++m) {
          c0h[m] = cvtpk_bf16(sB[kt][4 * m + 0], sB[kt][4 * m + 1]);
          c1h[m] = cvtpk_bf16(sB[kt][4 * m + 2], sB[kt][4 * m + 3]);
        }
#pragma unroll
        for (int sI = 0; sI < 2; ++sI) {
          unsigned dw0, dw1, dw2, dw3;
          xsw<S2>(c0h[2 * sI], c0h[2 * sI + 1], dw0, dw2);
          xsw<S2>(c1h[2 * sI], c1h[2 * sI + 1], dw1, dw3);
          union U { uint4 u; short8 s8; } FH;
          FH.u = make_uint4(dw0, dw1, dw2, dw3);
          fragh[kt * 2 + sI] = FH.s8;
        }
      }
      __builtin_amdgcn_s_setprio(1);
#pragma unroll
      for (int ks = 0; ks < 4; ++ks) {
        short8 vf0 = *(const short8*)(kv0 + curOff + 24576 + va[ks]);
        short8 vf1 = *(const short8*)(kv0 + curOff + 24576 + 4096 + va[ks]);
        o[0] = MFMA32(vf0, fragh[ks], o[0]);
        o[1] = MFMA32(vf1, fragh[ks], o[1]);
        osum = MFMA32(ones, fragh[ks], osum);
      }
      __builtin_amdgcn_s_setprio(0);
    }

    __syncthreads();  // all reads of buf[curOff] (PV) done
    if (it < 14) {    // stage tile it+2 into buf[curOff]
#pragma unroll
      for (int c = 0; c < 4; ++c) {
        *(short8*)(kv0 + curOff + dstK[c]) = sk[c];
        *(short8*)(kv0 + curOff + dstV[c]) = sv[c];
      }
      if (it < 13) {  // prefetch tile it+3
#pragma unroll
        for (int c = 0; c < 4; ++c) {
          koff[c] += 8192; voff[c] += 128;
          sk[c] = *(const short8*)(Khb + koff[c]);
          sv[c] = *(const short8*)(Vhb + voff[c]);
        }
      }
    }
    __syncthreads();  // staged writes visible for next half's QK^T
  };

  for (int itp = 0; itp < 8; ++itp) {
    half(2 * itp, sE, sEb, sO, sOb, 0, 32768);
    half(2 * itp + 1, sO, sOb, sE, sEb, 32768, 0);
  }

  // ---- epilogue: normalize by osum[0] ----
  const float lsum = osum[0];
  const float invl = lsum > 0.0f ? 1.0f / lsum : 0.0f;
#pragma unroll
  for (int dt = 0; dt < 2; ++dt)
#pragma unroll
    for (int m = 0; m < 4; ++m) {
      float4 v;
      v.x = o[dt][4 * m + 0] * invl;
      v.y = o[dt][4 * m + 1] * invl;
      v.z = o[dt][4 * m + 2] * invl;
      v.w = o[dt][4 * m + 3] * invl;
      const int d = dt * 32 + m * 8 + 4 * hi;
      *(float4*)&Ob[(size_t)qglob * 512 + d] = v;
    }
}

// ---------------- Kernel 2: flash attention ----------------
__global__ __launch_bounds__(256, 2) void attn_kernel(
    const unsigned short* __restrict__ Qh,
    const unsigned short* __restrict__ Kh, const unsigned short* __restrict__ Vh,
    const unsigned long long* __restrict__ Mp, float* __restrict__ out) {
  __shared__ __align__(16) unsigned short kvb[2][4][64][64];  // 64 KB double buffer

  const int hi = (threadIdx.x & 63) >> 5;
  unsigned ta = 1u + (unsigned)hi;
  unsigned tb = 3u + (unsigned)hi;
  permswap(ta, tb);
  const bool s2 = (__builtin_amdgcn_readfirstlane(ta) == 1u);

  if (s2) attn_body<true>(kvb, Qh, Kh, Vh, Mp, out);
  else    attn_body<false>(kvb, Qh, Kh, Vh, Mp, out);
}

extern "C" void kernel_launch(void* const* d_in, const int* in_sizes, int n_in,
                              void* d_out, int out_size, void* d_ws, size_t ws_size,
                              hipStream_t stream) {
  const float* x = (const float*)d_in[0];
  const void* mask = d_in[1];
  const float* Wq = (const float*)d_in[2];
  const float* Wk = (const float*)d_in[3];
  const float* Wv = (const float*)d_in[4];
  float* out = (float*)d_out;

  const size_t PLANE = (size_t)NBH * NSEQ * DH;  // 4,194,304 ushorts
  unsigned short* Qh = (unsigned short*)d_ws;
  unsigned short* Kh = Qh + PLANE;
  unsigned short* Vh = Kh + PLANE;
  unsigned short* xh = Vh + PLANE;
  unsigned short* xl = xh + PLANE;
  unsigned short* wh = xl + PLANE;               // 3 * 262,144 ushorts
  unsigned short* wl = wh + 786432;
  unsigned long long* Mp = (unsigned long long*)(wl + 786432);  // 2 MB

  prep_kernel<<<1024, 256, 0, stream>>>(mask, Mp, x, Wq, Wk, Wv, xh, xl, wh, wl);
  proj_kernel<<<dim3(128, 8), 256, 0, stream>>>(xh, xl, wh, wl, Qh, Kh, Vh);
  attn_kernel<<<512, 256, 0, stream>>>(Qh, Kh, Vh, Mp, out);
}

// Round 18
// 124.461 us; speedup vs baseline: 1.3626x; 1.3626x over previous
//
#include <hip/hip_runtime.h>

// Attention_29231547416680: B=4, N=2048, CH=512, H=8, D=64, fp32 in/out.
// R18 = R16 with per-tile softmax (decoupled A/B pipelines inside each iter):
//       softmax-A VALU overlaps QK^T-B MFMAs; softmax-B overlaps PV-A MFMAs.
//       Same math as R14 (sequential 64-row tiles). No lambdas, no extra regs
//       (R17's array-ref lambda spilled to scratch: WRITE_SIZE 192MB).
//       prep/proj byte-identical to R16.

typedef float f32x4 __attribute__((ext_vector_type(4)));
typedef float f32x16 __attribute__((ext_vector_type(16)));
typedef short short8 __attribute__((ext_vector_type(8)));

#define MFMA16(a, b, c) __builtin_amdgcn_mfma_f32_16x16x32_bf16((a), (b), (c), 0, 0, 0)
#define MFMA32(a, b, c) __builtin_amdgcn_mfma_f32_32x32x16_bf16((a), (b), (c), 0, 0, 0)

#if __has_builtin(__builtin_amdgcn_exp2f)
#define EXP2(x) __builtin_amdgcn_exp2f(x)
#else
#define EXP2(x) exp2f(x)
#endif

#define NBH 32
#define NSEQ 2048
#define DH 64

__device__ __forceinline__ unsigned short f2bf(float f) {
  unsigned int u = __float_as_uint(f);
  u += 0x7fffu + ((u >> 16) & 1u);  // RTNE
  return (unsigned short)(u >> 16);
}
__device__ __forceinline__ float bf2f(unsigned short h) {
  return __uint_as_float(((unsigned int)h) << 16);
}
__device__ __forceinline__ void split_bf16(float f, unsigned short& hi, unsigned short& lo) {
  hi = f2bf(f);
  lo = f2bf(f - bf2f(hi));
}

__device__ __forceinline__ unsigned cvtpk_bf16(float a, float b) {
  unsigned d;
  asm("v_cvt_pk_bf16_f32 %0, %1, %2" : "=v"(d) : "v"(a), "v"(b));
  return d;
}
__device__ __forceinline__ void permswap(unsigned& a, unsigned& b) {
  asm("v_permlane32_swap_b32 %0, %1" : "+v"(a), "+v"(b));
}
// lo = (ce.row0 | co.row0), hi = (ce.row1 | co.row1); S2 selects HW direction.
template <bool S2>
__device__ __forceinline__ void xsw(unsigned ce, unsigned co, unsigned& lo, unsigned& hi) {
  if (S2) { permswap(ce, co); }
  else    { permswap(co, ce); }
  lo = ce;
  hi = co;
}

// async global -> LDS, 16 bytes per lane; LDS dst = wave-uniform base + lane*16.
typedef __attribute__((address_space(1))) const unsigned int as1_u32;
typedef __attribute__((address_space(3))) unsigned int as3_u32;
__device__ __forceinline__ void gld_lds16(const unsigned short* g, unsigned short* l) {
  __builtin_amdgcn_global_load_lds((as1_u32*)g, (as3_u32*)l, 16, 0, 0);
}

// ---------------- prep: mask bit-pack + x/W hi-lo split (R16 verbatim) ----------------
__global__ __launch_bounds__(256) void prep_kernel(
    const void* __restrict__ mraw, unsigned long long* __restrict__ Mp,
    const float* __restrict__ x,
    const float* __restrict__ Wq, const float* __restrict__ Wk, const float* __restrict__ Wv,
    unsigned short* __restrict__ xh, unsigned short* __restrict__ xl,
    unsigned short* __restrict__ wh, unsigned short* __restrict__ wl) {
  const int tid = threadIdx.x;
  __shared__ int s_bad;
  if (tid == 0) s_bad = 0;
  __syncthreads();
  const unsigned int* mw32 = (const unsigned int*)mraw;
  {
    unsigned int w0 = mw32[tid], w1 = mw32[256 + tid];
    bool ok = (w0 == 0u || w0 == 1u || w0 == 0x3f800000u) &&
              (w1 == 0u || w1 == 1u || w1 == 0x3f800000u);
    if (!ok) s_bad = 1;
  }
  __syncthreads();
  const size_t e0 = (size_t)blockIdx.x * 16384 + (size_t)tid * 64;
  unsigned long long bits = 0ull;
  if (s_bad == 0) {
    const uint4* p = (const uint4*)mw32 + (e0 >> 2);
#pragma unroll
    for (int j = 0; j < 16; ++j) {
      uint4 v = p[j];
      unsigned nib = (v.x != 0u) | ((v.y != 0u) << 1) | ((v.z != 0u) << 2) | ((v.w != 0u) << 3);
      bits |= (unsigned long long)nib << (j * 4);
    }
  } else {
    const uint4* p = (const uint4*)((const unsigned char*)mraw + e0);
#pragma unroll
    for (int j = 0; j < 4; ++j) {
      uint4 v = p[j];
      unsigned dw[4] = {v.x, v.y, v.z, v.w};
#pragma unroll
      for (int d = 0; d < 4; ++d) {
        unsigned nib = (((dw[d]) & 0xffu) != 0u) | ((((dw[d] >> 8) & 0xffu) != 0u) << 1) |
                       ((((dw[d] >> 16) & 0xffu) != 0u) << 2) | ((((dw[d] >> 24) & 0xffu) != 0u) << 3);
        bits |= (unsigned long long)nib << ((j * 4 + d) * 4);
      }
    }
  }
  Mp[e0 >> 6] = bits;

  const int gtid = blockIdx.x * 256 + tid;
  const float4* x4 = (const float4*)x;
#pragma unroll
  for (int rep = 0; rep < 4; ++rep) {
    int i = gtid + rep * 262144;
    float4 v = x4[i];
    unsigned short h0, l0, h1, l1, h2, l2, h3, l3;
    split_bf16(v.x, h0, l0); split_bf16(v.y, h1, l1);
    split_bf16(v.z, h2, l2); split_bf16(v.w, h3, l3);
    *(ushort4*)&xh[(size_t)i * 4] = make_ushort4(h0, h1, h2, h3);
    *(ushort4*)&xl[(size_t)i * 4] = make_ushort4(l0, l1, l2, l3);
  }
  if (gtid < 65536) {
    const float* Ws[3] = {Wq, Wk, Wv};
#pragma unroll
    for (int z = 0; z < 3; ++z) {
      float4 v = ((const float4*)Ws[z])[gtid];
      unsigned short h0, l0, h1, l1, h2, l2, h3, l3;
      split_bf16(v.x, h0, l0); split_bf16(v.y, h1, l1);
      split_bf16(v.z, h2, l2); split_bf16(v.w, h3, l3);
      size_t o = (size_t)z * 262144 + (size_t)gtid * 4;
      *(ushort4*)&wh[o] = make_ushort4(h0, h1, h2, h3);
      *(ushort4*)&wl[o] = make_ushort4(l0, l1, l2, l3);
    }
  }
}

// ---------------- Kernel 1: QKV projection (R16 verbatim) ----------------
__global__ __launch_bounds__(256, 4) void proj_kernel(
    const unsigned short* __restrict__ xh, const unsigned short* __restrict__ xl,
    const unsigned short* __restrict__ wh, const unsigned short* __restrict__ wl,
    unsigned short* __restrict__ Qh, unsigned short* __restrict__ Kh,
    unsigned short* __restrict__ Vh) {
  const int tid = threadIdx.x;
  const int w = tid >> 6, l = tid & 63;
  const int m0 = blockIdx.x * 64;
  const int h = blockIdx.y;
  const int lrow = l & 15, lg = l >> 4;
  const int rw = (w >> 1) * 32, cw = (w & 1) * 32;

  union LDSU {
    unsigned short tiles[8][64][32];  // 32 KB staging
    unsigned short ob[64][72];        // epilogue bounce
  };
  __shared__ __align__(16) LDSU u;

  f32x4 acc[3][2][2] = {};

  const unsigned short* planes[8] = {xh, xl, wh, wl, wh + 262144, wl + 262144,
                                     wh + 524288, wl + 524288};
  const int rowb[8] = {m0, m0, h * 64, h * 64, h * 64, h * 64, h * 64, h * 64};
  const int srow = l >> 2, scol = (l & 3) * 8;
  const unsigned short* s0 = planes[2 * w] + (size_t)(rowb[2 * w] + srow) * 512 + scol;
  const unsigned short* s1 = planes[2 * w + 1] + (size_t)(rowb[2 * w + 1] + srow) * 512 + scol;
  unsigned short* d0 = &u.tiles[2 * w][0][0];
  unsigned short* d1 = &u.tiles[2 * w + 1][0][0];

  for (int k0 = 0; k0 < 512; k0 += 32) {
    __syncthreads();
#pragma unroll
    for (int c = 0; c < 4; ++c) {
      gld_lds16(s0 + k0 + c * 8192, d0 + c * 512);
      gld_lds16(s1 + k0 + c * 8192, d1 + c * 512);
    }
    __syncthreads();

    short8 axh[2], axl[2];
#pragma unroll
    for (int t = 0; t < 2; ++t) {
      axh[t] = *(const short8*)&u.tiles[0][rw + 16 * t + lrow][lg * 8];
      axl[t] = *(const short8*)&u.tiles[1][rw + 16 * t + lrow][lg * 8];
    }
#pragma unroll
    for (int z = 0; z < 3; ++z) {
      short8 bh[2], bl[2];
#pragma unroll
      for (int t = 0; t < 2; ++t) {
        bh[t] = *(const short8*)&u.tiles[2 + 2 * z][cw + 16 * t + lrow][lg * 8];
        bl[t] = *(const short8*)&u.tiles[3 + 2 * z][cw + 16 * t + lrow][lg * 8];
      }
#pragma unroll
      for (int tm = 0; tm < 2; ++tm)
#pragma unroll
        for (int tn = 0; tn < 2; ++tn) {
          acc[z][tm][tn] = MFMA16(axh[tm], bh[tn], acc[z][tm][tn]);
          acc[z][tm][tn] = MFMA16(axh[tm], bl[tn], acc[z][tm][tn]);
          acc[z][tm][tn] = MFMA16(axl[tm], bh[tn], acc[z][tm][tn]);
        }
    }
  }

  const float qsc = 1.4426950408889634f * 0.08838834764831845f;  // log2e/sqrt(128)
  const int orow = tid >> 2, oc = (tid & 3) * 16;
  const int b = m0 >> 11, n0 = m0 & 2047, bhid = b * 8 + h;
#pragma unroll
  for (int z = 0; z < 3; ++z) {
    __syncthreads();
#pragma unroll
    for (int tm = 0; tm < 2; ++tm)
#pragma unroll
      for (int tn = 0; tn < 2; ++tn) {
        int dcol = cw + tn * 16 + lrow;
        int nl = rw + tm * 16 + lg * 4;
#pragma unroll
        for (int r = 0; r < 4; ++r) {
          float v = acc[z][tm][tn][r];
          if (z == 0) v *= qsc;
          if (z < 2) u.ob[nl + r][dcol] = f2bf(v);
          else       u.ob[dcol][nl + r] = f2bf(v);  // V: transposed
        }
      }
    __syncthreads();
    if (z < 2) {
      unsigned short* O = (z == 0) ? Qh : Kh;
      size_t base = ((size_t)bhid * 2048 + n0 + orow) * 64 + oc;
      *(short8*)&O[base] = *(const short8*)&u.ob[orow][oc];
      *(short8*)&O[base + 8] = *(const short8*)&u.ob[orow][oc + 8];
    } else {
      size_t vb = ((size_t)bhid * 64 + orow) * 2048 + n0 + oc;
      *(short8*)&Vh[vb] = *(const short8*)&u.ob[orow][oc];
      *(short8*)&Vh[vb + 8] = *(const short8*)&u.ob[orow][oc + 8];
    }
  }
}

// ---------------- attention body (per-tile softmax, 2-tile in-iter overlap) ----------------
template <bool S2>
__device__ __forceinline__ void attn_body(
    unsigned short (&kvb)[2][4][64][64],
    const unsigned short* __restrict__ Qh,
    const unsigned short* __restrict__ Kh, const unsigned short* __restrict__ Vh,
    const unsigned long long* __restrict__ Mp, float* __restrict__ out) {
  const int tid = threadIdx.x;
  const int w = tid >> 6, l = tid & 63;
  const int wl = blockIdx.x;
  const int rm = (wl & 7) * 64 + (wl >> 3);  // XCD swizzle (512 = 8*64, bijective)
  const int q0 = (rm & 15) * 128;
  const int bh = rm >> 4;
  const int b = bh >> 3, h = bh & 7;
  const int l31 = l & 31, hi = l >> 5;
  const int swz = (l31 & 7) << 4;

  const unsigned short* Qhb = Qh + (size_t)bh * NSEQ * DH;
  const unsigned short* Khb = Kh + (size_t)bh * NSEQ * DH;
  const unsigned short* Vhb = Vh + (size_t)bh * DH * NSEQ;
  const unsigned long long* Mb = Mp + (size_t)b * NSEQ * 32;
  float* Ob = out + (size_t)b * NSEQ * 512 + h * 64;

  // buffer = 4 sub-planes x 8KB: Ka(0) Kb(8192) Va(16384) Vb(24576); dbuf stride 32768.
  char* kv0 = (char*)&kvb[0][0][0][0];

  int va[4];
#pragma unroll
  for (int d = 0; d < 4; ++d) va[d] = l31 * 128 + (((d * 32) | (hi * 16)) ^ swz);

  const size_t qoff = (size_t)(q0 + w * 32 + l31) * 64 + hi * 8;
  short8 qh[4];
#pragma unroll
  for (int d = 0; d < 4; ++d) qh[d] = *(const short8*)(Qhb + qoff + d * 16);

  short8 ones;
#pragma unroll
  for (int j = 0; j < 8; ++j) ones[j] = (short)0x3F80;

  f32x16 o[2] = {};
  f32x16 osum = {};  // element 0 = running row-sum l
  float mrun = -1e30f;
  const int qglob = q0 + w * 32 + l31;

  // staging: 256 threads x 4 K-chunks + 4 V-chunks of short8
  const int row0 = tid >> 3, colx = (tid & 7) * 8;
  const int swst = (colx * 2) ^ ((row0 & 7) << 4);
  int dstK[4], dstV[4];
#pragma unroll
  for (int c = 0; c < 4; ++c) {
    const int rsub = (c & 1) * 32 + row0;
    dstK[c] = (c >> 1) * 8192 + rsub * 128 + swst;
    dstV[c] = 16384 + (c >> 1) * 8192 + rsub * 128 + swst;
  }
  size_t koff[4], voff[4];
#pragma unroll
  for (int c = 0; c < 4; ++c) {
    koff[c] = (size_t)(c * 32 + row0) * 64 + colx;
    voff[c] = (size_t)((c & 1) * 32 + row0) * 2048 + (c >> 1) * 64 + colx;
  }

  short8 sk[4], sv[4];
#pragma unroll
  for (int c = 0; c < 4; ++c) {
    sk[c] = *(const short8*)(Khb + koff[c]);
    sv[c] = *(const short8*)(Vhb + voff[c]);
  }
#pragma unroll
  for (int c = 0; c < 4; ++c) {
    *(short8*)(kv0 + dstK[c]) = sk[c];
    *(short8*)(kv0 + dstV[c]) = sv[c];
  }
#pragma unroll
  for (int c = 0; c < 4; ++c) {
    koff[c] += 8192; voff[c] += 128;
    sk[c] = *(const short8*)(Khb + koff[c]);
    sv[c] = *(const short8*)(Vhb + voff[c]);
  }
  __syncthreads();

  for (int it = 0; it < 16; ++it) {
    char* cur = kv0 + (size_t)(it & 1) * 32768;
    if (it < 15) {
      char* nb = kv0 + (size_t)((it + 1) & 1) * 32768;
#pragma unroll
      for (int c = 0; c < 4; ++c) {
        *(short8*)(nb + dstK[c]) = sk[c];
        *(short8*)(nb + dstV[c]) = sv[c];
      }
      if (it < 14) {
#pragma unroll
        for (int c = 0; c < 4; ++c) {
          koff[c] += 8192; voff[c] += 128;
          sk[c] = *(const short8*)(Khb + koff[c]);
          sv[c] = *(const short8*)(Vhb + voff[c]);
        }
      }
    }

    const unsigned long long mwA = Mb[(size_t)qglob * 32 + 2 * it];
    const unsigned long long mwB = Mb[(size_t)qglob * 32 + 2 * it + 1];

    // ---- QK^T both tiles (A first so softmax-A can start while B drains) ----
    f32x16 sA[2] = {}, sB[2] = {};
    __builtin_amdgcn_s_setprio(1);
#pragma unroll
    for (int d = 0; d < 4; ++d)
#pragma unroll
      for (int kt = 0; kt < 2; ++kt) {
        short8 kfa = *(const short8*)(cur + kt * 4096 + va[d]);
        sA[kt] = MFMA32(kfa, qh[d], sA[kt]);
      }
#pragma unroll
    for (int d = 0; d < 4; ++d)
#pragma unroll
      for (int kt = 0; kt < 2; ++kt) {
        short8 kfb = *(const short8*)(cur + 8192 + kt * 4096 + va[d]);
        sB[kt] = MFMA32(kfb, qh[d], sB[kt]);
      }
    __builtin_amdgcn_s_setprio(0);

    // ---- softmax-A (VALU; scheduler interleaves with QK^T-B MFMA drain) ----
#pragma unroll
    for (int kt = 0; kt < 2; ++kt)
#pragma unroll
      for (int m = 0; m < 4; ++m) {
        unsigned nib = ((unsigned)(mwA >> (kt * 32 + m * 8 + 4 * hi))) & 0xFu;
#pragma unroll
        for (int r = 0; r < 4; ++r)
          sA[kt][4 * m + r] = ((nib >> r) & 1u) ? -1e30f : sA[kt][4 * m + r];
      }
    float mxA = sA[0][0];
#pragma unroll
    for (int kt = 0; kt < 2; ++kt)
#pragma unroll
      for (int e = (kt == 0 ? 1 : 0); e < 16; ++e)
        mxA = fmaxf(mxA, sA[kt][e]);
    mxA = fmaxf(mxA, __shfl_xor(mxA, 32));
    const bool growA = __any(mxA > mrun + 11.0f);
    const float mnewA = growA ? fmaxf(mrun, mxA) : mrun;
#pragma unroll
    for (int kt = 0; kt < 2; ++kt)
#pragma unroll
      for (int e = 0; e < 16; ++e) sA[kt][e] = EXP2(sA[kt][e] - mnewA);
    if (growA) {
      float sc = EXP2(mrun - mnewA);
      mrun = mnewA;
      osum[0] *= sc;
#pragma unroll
      for (int dt = 0; dt < 2; ++dt)
#pragma unroll
        for (int e = 0; e < 16; ++e) o[dt][e] *= sc;
    }

    // ---- pack-A + PV-A (MFMA; softmax-B VALU below interleaves) ----
    {
      short8 fragh[4];
#pragma unroll
      for (int kt = 0; kt < 2; ++kt) {
        unsigned c0h[4], c1h[4];
#pragma unroll
        for (int m = 0; m < 4; ++m) {
          c0h[m] = cvtpk_bf16(sA[kt][4 * m + 0], sA[kt][4 * m + 1]);
          c1h[m] = cvtpk_bf16(sA[kt][4 * m + 2], sA[kt][4 * m + 3]);
        }
#pragma unroll
        for (int sI = 0; sI < 2; ++sI) {
          unsigned dw0, dw1, dw2, dw3;
          xsw<S2>(c0h[2 * sI], c0h[2 * sI + 1], dw0, dw2);
          xsw<S2>(c1h[2 * sI], c1h[2 * sI + 1], dw1, dw3);
          union U { uint4 u; short8 s8; } FH;
          FH.u = make_uint4(dw0, dw1, dw2, dw3);
          fragh[kt * 2 + sI] = FH.s8;
        }
      }
      __builtin_amdgcn_s_setprio(1);
#pragma unroll
      for (int ks = 0; ks < 4; ++ks) {
        short8 vf0 = *(const short8*)(cur + 16384 + va[ks]);
        short8 vf1 = *(const short8*)(cur + 16384 + 4096 + va[ks]);
        o[0] = MFMA32(vf0, fragh[ks], o[0]);
        o[1] = MFMA32(vf1, fragh[ks], o[1]);
        osum = MFMA32(ones, fragh[ks], osum);
      }
      __builtin_amdgcn_s_setprio(0);
    }

    // ---- softmax-B (interleaves with PV-A drain) ----
#pragma unroll
    for (int kt = 0; kt < 2; ++kt)
#pragma unroll
      for (int m = 0; m < 4; ++m) {
        unsigned nib = ((unsigned)(mwB >> (kt * 32 + m * 8 + 4 * hi))) & 0xFu;
#pragma unroll
        for (int r = 0; r < 4; ++r)
          sB[kt][4 * m + r] = ((nib >> r) & 1u) ? -1e30f : sB[kt][4 * m + r];
      }
    float mxB = sB[0][0];
#pragma unroll
    for (int kt = 0; kt < 2; ++kt)
#pragma unroll
      for (int e = (kt == 0 ? 1 : 0); e < 16; ++e)
        mxB = fmaxf(mxB, sB[kt][e]);
    mxB = fmaxf(mxB, __shfl_xor(mxB, 32));
    const bool growB = __any(mxB > mrun + 11.0f);
    const float mnewB = growB ? fmaxf(mrun, mxB) : mrun;
#pragma unroll
    for (int kt = 0; kt < 2; ++kt)
#pragma unroll
      for (int e = 0; e < 16; ++e) sB[kt][e] = EXP2(sB[kt][e] - mnewB);
    if (growB) {
      float sc = EXP2(mrun - mnewB);
      mrun = mnewB;
      osum[0] *= sc;
#pragma unroll
      for (int dt = 0; dt < 2; ++dt)
#pragma unroll
        for (int e = 0; e < 16; ++e) o[dt][e] *= sc;
    }

    // ---- pack-B + PV-B ----
    {
      short8 fragh[4];
#pragma unroll
      for (int kt = 0; kt < 2; ++kt) {
        unsigned c0h[4], c1h[4];
#pragma unroll
        for (int m = 0; m < 4; ++m) {
          c0h[m] = cvtpk_bf16(sB[kt][4 * m + 0], sB[kt][4 * m + 1]);
          c1h[m] = cvtpk_bf16(sB[kt][4 * m + 2], sB[kt][4 * m + 3]);
        }
#pragma unroll
        for (int sI = 0; sI < 2; ++sI) {
          unsigned dw0, dw1, dw2, dw3;
          xsw<S2>(c0h[2 * sI], c0h[2 * sI + 1], dw0, dw2);
          xsw<S2>(c1h[2 * sI], c1h[2 * sI + 1], dw1, dw3);
          union U { uint4 u; short8 s8; } FH;
          FH.u = make_uint4(dw0, dw1, dw2, dw3);
          fragh[kt * 2 + sI] = FH.s8;
        }
      }
      __builtin_amdgcn_s_setprio(1);
#pragma unroll
      for (int ks = 0; ks < 4; ++ks) {
        short8 vf0 = *(const short8*)(cur + 24576 + va[ks]);
        short8 vf1 = *(const short8*)(cur + 24576 + 4096 + va[ks]);
        o[0] = MFMA32(vf0, fragh[ks], o[0]);
        o[1] = MFMA32(vf1, fragh[ks], o[1]);
        osum = MFMA32(ones, fragh[ks], osum);
      }
      __builtin_amdgcn_s_setprio(0);
    }

    __syncthreads();
  }

  // ---- epilogue: normalize by osum[0] ----
  const float lsum = osum[0];
  const float invl = lsum > 0.0f ? 1.0f / lsum : 0.0f;
#pragma unroll
  for (int dt = 0; dt < 2; ++dt)
#pragma unroll
    for (int m = 0; m < 4; ++m) {
      float4 v;
      v.x = o[dt][4 * m + 0] * invl;
      v.y = o[dt][4 * m + 1] * invl;
      v.z = o[dt][4 * m + 2] * invl;
      v.w = o[dt][4 * m + 3] * invl;
      const int d = dt * 32 + m * 8 + 4 * hi;
      *(float4*)&Ob[(size_t)qglob * 512 + d] = v;
    }
}

// ---------------- Kernel 2: flash attention ----------------
__global__ __launch_bounds__(256, 2) void attn_kernel(
    const unsigned short* __restrict__ Qh,
    const unsigned short* __restrict__ Kh, const unsigned short* __restrict__ Vh,
    const unsigned long long* __restrict__ Mp, float* __restrict__ out) {
  __shared__ __align__(16) unsigned short kvb[2][4][64][64];  // 64 KB double buffer

  const int hi = (threadIdx.x & 63) >> 5;
  unsigned ta = 1u + (unsigned)hi;
  unsigned tb = 3u + (unsigned)hi;
  permswap(ta, tb);
  const bool s2 = (__builtin_amdgcn_readfirstlane(ta) == 1u);

  if (s2) attn_body<true>(kvb, Qh, Kh, Vh, Mp, out);
  else    attn_body<false>(kvb, Qh, Kh, Vh, Mp, out);
}

extern "C" void kernel_launch(void* const* d_in, const int* in_sizes, int n_in,
                              void* d_out, int out_size, void* d_ws, size_t ws_size,
                              hipStream_t stream) {
  const float* x = (const float*)d_in[0];
  const void* mask = d_in[1];
  const float* Wq = (const float*)d_in[2];
  const float* Wk = (const float*)d_in[3];
  const float* Wv = (const float*)d_in[4];
  float* out = (float*)d_out;

  const size_t PLANE = (size_t)NBH * NSEQ * DH;  // 4,194,304 ushorts
  unsigned short* Qh = (unsigned short*)d_ws;
  unsigned short* Kh = Qh + PLANE;
  unsigned short* Vh = Kh + PLANE;
  unsigned short* xh = Vh + PLANE;
  unsigned short* xl = xh + PLANE;
  unsigned short* wh = xl + PLANE;               // 3 * 262,144 ushorts
  unsigned short* wl = wh + 786432;
  unsigned long long* Mp = (unsigned long long*)(wl + 786432);  // 2 MB

  prep_kernel<<<1024, 256, 0, stream>>>(mask, Mp, x, Wq, Wk, Wv, xh, xl, wh, wl);
  proj_kernel<<<dim3(128, 8), 256, 0, stream>>>(xh, xl, wh, wl, Qh, Kh, Vh);
  attn_kernel<<<512, 256, 0, stream>>>(Qh, Kh, Vh, Mp, out);
}

// Round 19
// 116.434 us; speedup vs baseline: 1.4566x; 1.0689x over previous
//
#include <hip/hip_runtime.h>

// Attention_29231547416680: B=4, N=2048, CH=512, H=8, D=64, fp32 in/out.
// R19 = R18 with x single-bf16: xl plane dropped (prep writes halve), proj
//       A-operand is xh only -> 7 staged tiles (28KB), 24 MFMA16/k-step (-33%).
//       Error budget: delta-q from bf16-x ~ same order as Q's own bf16 store;
//       R18's per-tile max freed headroom (absmax 1.1e-3). attn = R18 verbatim.

typedef float f32x4 __attribute__((ext_vector_type(4)));
typedef float f32x16 __attribute__((ext_vector_type(16)));
typedef short short8 __attribute__((ext_vector_type(8)));

#define MFMA16(a, b, c) __builtin_amdgcn_mfma_f32_16x16x32_bf16((a), (b), (c), 0, 0, 0)
#define MFMA32(a, b, c) __builtin_amdgcn_mfma_f32_32x32x16_bf16((a), (b), (c), 0, 0, 0)

#if __has_builtin(__builtin_amdgcn_exp2f)
#define EXP2(x) __builtin_amdgcn_exp2f(x)
#else
#define EXP2(x) exp2f(x)
#endif

#define NBH 32
#define NSEQ 2048
#define DH 64

__device__ __forceinline__ unsigned short f2bf(float f) {
  unsigned int u = __float_as_uint(f);
  u += 0x7fffu + ((u >> 16) & 1u);  // RTNE
  return (unsigned short)(u >> 16);
}
__device__ __forceinline__ float bf2f(unsigned short h) {
  return __uint_as_float(((unsigned int)h) << 16);
}
__device__ __forceinline__ void split_bf16(float f, unsigned short& hi, unsigned short& lo) {
  hi = f2bf(f);
  lo = f2bf(f - bf2f(hi));
}

__device__ __forceinline__ unsigned cvtpk_bf16(float a, float b) {
  unsigned d;
  asm("v_cvt_pk_bf16_f32 %0, %1, %2" : "=v"(d) : "v"(a), "v"(b));
  return d;
}
__device__ __forceinline__ void permswap(unsigned& a, unsigned& b) {
  asm("v_permlane32_swap_b32 %0, %1" : "+v"(a), "+v"(b));
}
// lo = (ce.row0 | co.row0), hi = (ce.row1 | co.row1); S2 selects HW direction.
template <bool S2>
__device__ __forceinline__ void xsw(unsigned ce, unsigned co, unsigned& lo, unsigned& hi) {
  if (S2) { permswap(ce, co); }
  else    { permswap(co, ce); }
  lo = ce;
  hi = co;
}

// async global -> LDS, 16 bytes per lane; LDS dst = wave-uniform base + lane*16.
typedef __attribute__((address_space(1))) const unsigned int as1_u32;
typedef __attribute__((address_space(3))) unsigned int as3_u32;
__device__ __forceinline__ void gld_lds16(const unsigned short* g, unsigned short* l) {
  __builtin_amdgcn_global_load_lds((as1_u32*)g, (as3_u32*)l, 16, 0, 0);
}

// ---------------- prep: mask bit-pack + x(single)/W(hi-lo) convert ----------------
__global__ __launch_bounds__(256) void prep_kernel(
    const void* __restrict__ mraw, unsigned long long* __restrict__ Mp,
    const float* __restrict__ x,
    const float* __restrict__ Wq, const float* __restrict__ Wk, const float* __restrict__ Wv,
    unsigned short* __restrict__ xh,
    unsigned short* __restrict__ wh, unsigned short* __restrict__ wl) {
  const int tid = threadIdx.x;
  __shared__ int s_bad;
  if (tid == 0) s_bad = 0;
  __syncthreads();
  const unsigned int* mw32 = (const unsigned int*)mraw;
  {
    unsigned int w0 = mw32[tid], w1 = mw32[256 + tid];
    bool ok = (w0 == 0u || w0 == 1u || w0 == 0x3f800000u) &&
              (w1 == 0u || w1 == 1u || w1 == 0x3f800000u);
    if (!ok) s_bad = 1;
  }
  __syncthreads();
  const size_t e0 = (size_t)blockIdx.x * 16384 + (size_t)tid * 64;
  unsigned long long bits = 0ull;
  if (s_bad == 0) {
    const uint4* p = (const uint4*)mw32 + (e0 >> 2);
#pragma unroll
    for (int j = 0; j < 16; ++j) {
      uint4 v = p[j];
      unsigned nib = (v.x != 0u) | ((v.y != 0u) << 1) | ((v.z != 0u) << 2) | ((v.w != 0u) << 3);
      bits |= (unsigned long long)nib << (j * 4);
    }
  } else {
    const uint4* p = (const uint4*)((const unsigned char*)mraw + e0);
#pragma unroll
    for (int j = 0; j < 4; ++j) {
      uint4 v = p[j];
      unsigned dw[4] = {v.x, v.y, v.z, v.w};
#pragma unroll
      for (int d = 0; d < 4; ++d) {
        unsigned nib = (((dw[d]) & 0xffu) != 0u) | ((((dw[d] >> 8) & 0xffu) != 0u) << 1) |
                       ((((dw[d] >> 16) & 0xffu) != 0u) << 2) | ((((dw[d] >> 24) & 0xffu) != 0u) << 3);
        bits |= (unsigned long long)nib << ((j * 4 + d) * 4);
      }
    }
  }
  Mp[e0 >> 6] = bits;

  const int gtid = blockIdx.x * 256 + tid;
  const float4* x4 = (const float4*)x;
#pragma unroll
  for (int rep = 0; rep < 4; ++rep) {
    int i = gtid + rep * 262144;
    float4 v = x4[i];
    *(ushort4*)&xh[(size_t)i * 4] =
        make_ushort4(f2bf(v.x), f2bf(v.y), f2bf(v.z), f2bf(v.w));
  }
  if (gtid < 65536) {
    const float* Ws[3] = {Wq, Wk, Wv};
#pragma unroll
    for (int z = 0; z < 3; ++z) {
      float4 v = ((const float4*)Ws[z])[gtid];
      unsigned short h0, l0, h1, l1, h2, l2, h3, l3;
      split_bf16(v.x, h0, l0); split_bf16(v.y, h1, l1);
      split_bf16(v.z, h2, l2); split_bf16(v.w, h3, l3);
      size_t o = (size_t)z * 262144 + (size_t)gtid * 4;
      *(ushort4*)&wh[o] = make_ushort4(h0, h1, h2, h3);
      *(ushort4*)&wl[o] = make_ushort4(l0, l1, l2, l3);
    }
  }
}

// ---------------- Kernel 1: QKV projection (x single, W split; 7 tiles) ----------------
__global__ __launch_bounds__(256, 4) void proj_kernel(
    const unsigned short* __restrict__ xh,
    const unsigned short* __restrict__ wh, const unsigned short* __restrict__ wl,
    unsigned short* __restrict__ Qh, unsigned short* __restrict__ Kh,
    unsigned short* __restrict__ Vh) {
  const int tid = threadIdx.x;
  const int w = tid >> 6, l = tid & 63;
  const int m0 = blockIdx.x * 64;
  const int h = blockIdx.y;
  const int lrow = l & 15, lg = l >> 4;
  const int rw = (w >> 1) * 32, cw = (w & 1) * 32;

  union LDSU {
    unsigned short tiles[7][64][32];  // 28 KB staging: 0 xh, 1+2z Wzh, 2+2z Wzl
    unsigned short ob[64][72];        // epilogue bounce
  };
  __shared__ __align__(16) LDSU u;

  f32x4 acc[3][2][2] = {};

  const unsigned short* planes[7] = {xh, wh, wl, wh + 262144, wl + 262144,
                                     wh + 524288, wl + 524288};
  const int rowb[7] = {m0, h * 64, h * 64, h * 64, h * 64, h * 64, h * 64};
  const int srow = l >> 2, scol = (l & 3) * 8;
  const int t0 = 2 * w, t1 = 2 * w + 1;
  const unsigned short* s0 = planes[t0] + (size_t)(rowb[t0] + srow) * 512 + scol;
  const unsigned short* s1 =
      (t1 < 7) ? planes[t1] + (size_t)(rowb[t1] + srow) * 512 + scol : nullptr;
  unsigned short* d0 = &u.tiles[t0][0][0];
  unsigned short* d1 = (t1 < 7) ? &u.tiles[t1][0][0] : nullptr;

  for (int k0 = 0; k0 < 512; k0 += 32) {
    __syncthreads();
#pragma unroll
    for (int c = 0; c < 4; ++c) {
      gld_lds16(s0 + k0 + c * 8192, d0 + c * 512);
      if (t1 < 7) gld_lds16(s1 + k0 + c * 8192, d1 + c * 512);
    }
    __syncthreads();

    short8 axh[2];
#pragma unroll
    for (int t = 0; t < 2; ++t)
      axh[t] = *(const short8*)&u.tiles[0][rw + 16 * t + lrow][lg * 8];
#pragma unroll
    for (int z = 0; z < 3; ++z) {
      short8 bh[2], bl[2];
#pragma unroll
      for (int t = 0; t < 2; ++t) {
        bh[t] = *(const short8*)&u.tiles[1 + 2 * z][cw + 16 * t + lrow][lg * 8];
        bl[t] = *(const short8*)&u.tiles[2 + 2 * z][cw + 16 * t + lrow][lg * 8];
      }
#pragma unroll
      for (int tm = 0; tm < 2; ++tm)
#pragma unroll
        for (int tn = 0; tn < 2; ++tn) {
          acc[z][tm][tn] = MFMA16(axh[tm], bh[tn], acc[z][tm][tn]);
          acc[z][tm][tn] = MFMA16(axh[tm], bl[tn], acc[z][tm][tn]);
        }
    }
  }

  const float qsc = 1.4426950408889634f * 0.08838834764831845f;  // log2e/sqrt(128)
  const int orow = tid >> 2, oc = (tid & 3) * 16;
  const int b = m0 >> 11, n0 = m0 & 2047, bhid = b * 8 + h;
#pragma unroll
  for (int z = 0; z < 3; ++z) {
    __syncthreads();
#pragma unroll
    for (int tm = 0; tm < 2; ++tm)
#pragma unroll
      for (int tn = 0; tn < 2; ++tn) {
        int dcol = cw + tn * 16 + lrow;
        int nl = rw + tm * 16 + lg * 4;
#pragma unroll
        for (int r = 0; r < 4; ++r) {
          float v = acc[z][tm][tn][r];
          if (z == 0) v *= qsc;
          if (z < 2) u.ob[nl + r][dcol] = f2bf(v);
          else       u.ob[dcol][nl + r] = f2bf(v);  // V: transposed
        }
      }
    __syncthreads();
    if (z < 2) {
      unsigned short* O = (z == 0) ? Qh : Kh;
      size_t base = ((size_t)bhid * 2048 + n0 + orow) * 64 + oc;
      *(short8*)&O[base] = *(const short8*)&u.ob[orow][oc];
      *(short8*)&O[base + 8] = *(const short8*)&u.ob[orow][oc + 8];
    } else {
      size_t vb = ((size_t)bhid * 64 + orow) * 2048 + n0 + oc;
      *(short8*)&Vh[vb] = *(const short8*)&u.ob[orow][oc];
      *(short8*)&Vh[vb + 8] = *(const short8*)&u.ob[orow][oc + 8];
    }
  }
}

// ---------------- attention body (R18 verbatim) ----------------
template <bool S2>
__device__ __forceinline__ void attn_body(
    unsigned short (&kvb)[2][4][64][64],
    const unsigned short* __restrict__ Qh,
    const unsigned short* __restrict__ Kh, const unsigned short* __restrict__ Vh,
    const unsigned long long* __restrict__ Mp, float* __restrict__ out) {
  const int tid = threadIdx.x;
  const int w = tid >> 6, l = tid & 63;
  const int wl = blockIdx.x;
  const int rm = (wl & 7) * 64 + (wl >> 3);  // XCD swizzle (512 = 8*64, bijective)
  const int q0 = (rm & 15) * 128;
  const int bh = rm >> 4;
  const int b = bh >> 3, h = bh & 7;
  const int l31 = l & 31, hi = l >> 5;
  const int swz = (l31 & 7) << 4;

  const unsigned short* Qhb = Qh + (size_t)bh * NSEQ * DH;
  const unsigned short* Khb = Kh + (size_t)bh * NSEQ * DH;
  const unsigned short* Vhb = Vh + (size_t)bh * DH * NSEQ;
  const unsigned long long* Mb = Mp + (size_t)b * NSEQ * 32;
  float* Ob = out + (size_t)b * NSEQ * 512 + h * 64;

  char* kv0 = (char*)&kvb[0][0][0][0];

  int va[4];
#pragma unroll
  for (int d = 0; d < 4; ++d) va[d] = l31 * 128 + (((d * 32) | (hi * 16)) ^ swz);

  const size_t qoff = (size_t)(q0 + w * 32 + l31) * 64 + hi * 8;
  short8 qh[4];
#pragma unroll
  for (int d = 0; d < 4; ++d) qh[d] = *(const short8*)(Qhb + qoff + d * 16);

  short8 ones;
#pragma unroll
  for (int j = 0; j < 8; ++j) ones[j] = (short)0x3F80;

  f32x16 o[2] = {};
  f32x16 osum = {};
  float mrun = -1e30f;
  const int qglob = q0 + w * 32 + l31;

  const int row0 = tid >> 3, colx = (tid & 7) * 8;
  const int swst = (colx * 2) ^ ((row0 & 7) << 4);
  int dstK[4], dstV[4];
#pragma unroll
  for (int c = 0; c < 4; ++c) {
    const int rsub = (c & 1) * 32 + row0;
    dstK[c] = (c >> 1) * 8192 + rsub * 128 + swst;
    dstV[c] = 16384 + (c >> 1) * 8192 + rsub * 128 + swst;
  }
  size_t koff[4], voff[4];
#pragma unroll
  for (int c = 0; c < 4; ++c) {
    koff[c] = (size_t)(c * 32 + row0) * 64 + colx;
    voff[c] = (size_t)((c & 1) * 32 + row0) * 2048 + (c >> 1) * 64 + colx;
  }

  short8 sk[4], sv[4];
#pragma unroll
  for (int c = 0; c < 4; ++c) {
    sk[c] = *(const short8*)(Khb + koff[c]);
    sv[c] = *(const short8*)(Vhb + voff[c]);
  }
#pragma unroll
  for (int c = 0; c < 4; ++c) {
    *(short8*)(kv0 + dstK[c]) = sk[c];
    *(short8*)(kv0 + dstV[c]) = sv[c];
  }
#pragma unroll
  for (int c = 0; c < 4; ++c) {
    koff[c] += 8192; voff[c] += 128;
    sk[c] = *(const short8*)(Khb + koff[c]);
    sv[c] = *(const short8*)(Vhb + voff[c]);
  }
  __syncthreads();

  for (int it = 0; it < 16; ++it) {
    char* cur = kv0 + (size_t)(it & 1) * 32768;
    if (it < 15) {
      char* nb = kv0 + (size_t)((it + 1) & 1) * 32768;
#pragma unroll
      for (int c = 0; c < 4; ++c) {
        *(short8*)(nb + dstK[c]) = sk[c];
        *(short8*)(nb + dstV[c]) = sv[c];
      }
      if (it < 14) {
#pragma unroll
        for (int c = 0; c < 4; ++c) {
          koff[c] += 8192; voff[c] += 128;
          sk[c] = *(const short8*)(Khb + koff[c]);
          sv[c] = *(const short8*)(Vhb + voff[c]);
        }
      }
    }

    const unsigned long long mwA = Mb[(size_t)qglob * 32 + 2 * it];
    const unsigned long long mwB = Mb[(size_t)qglob * 32 + 2 * it + 1];

    f32x16 sA[2] = {}, sB[2] = {};
    __builtin_amdgcn_s_setprio(1);
#pragma unroll
    for (int d = 0; d < 4; ++d)
#pragma unroll
      for (int kt = 0; kt < 2; ++kt) {
        short8 kfa = *(const short8*)(cur + kt * 4096 + va[d]);
        sA[kt] = MFMA32(kfa, qh[d], sA[kt]);
      }
#pragma unroll
    for (int d = 0; d < 4; ++d)
#pragma unroll
      for (int kt = 0; kt < 2; ++kt) {
        short8 kfb = *(const short8*)(cur + 8192 + kt * 4096 + va[d]);
        sB[kt] = MFMA32(kfb, qh[d], sB[kt]);
      }
    __builtin_amdgcn_s_setprio(0);

    // ---- softmax-A ----
#pragma unroll
    for (int kt = 0; kt < 2; ++kt)
#pragma unroll
      for (int m = 0; m < 4; ++m) {
        unsigned nib = ((unsigned)(mwA >> (kt * 32 + m * 8 + 4 * hi))) & 0xFu;
#pragma unroll
        for (int r = 0; r < 4; ++r)
          sA[kt][4 * m + r] = ((nib >> r) & 1u) ? -1e30f : sA[kt][4 * m + r];
      }
    float mxA = sA[0][0];
#pragma unroll
    for (int kt = 0; kt < 2; ++kt)
#pragma unroll
      for (int e = (kt == 0 ? 1 : 0); e < 16; ++e)
        mxA = fmaxf(mxA, sA[kt][e]);
    mxA = fmaxf(mxA, __shfl_xor(mxA, 32));
    const bool growA = __any(mxA > mrun + 11.0f);
    const float mnewA = growA ? fmaxf(mrun, mxA) : mrun;
#pragma unroll
    for (int kt = 0; kt < 2; ++kt)
#pragma unroll
      for (int e = 0; e < 16; ++e) sA[kt][e] = EXP2(sA[kt][e] - mnewA);
    if (growA) {
      float sc = EXP2(mrun - mnewA);
      mrun = mnewA;
      osum[0] *= sc;
#pragma unroll
      for (int dt = 0; dt < 2; ++dt)
#pragma unroll
        for (int e = 0; e < 16; ++e) o[dt][e] *= sc;
    }

    // ---- pack-A + PV-A ----
    {
      short8 fragh[4];
#pragma unroll
      for (int kt = 0; kt < 2; ++kt) {
        unsigned c0h[4], c1h[4];
#pragma unroll
        for (int m = 0; m < 4; ++m) {
          c0h[m] = cvtpk_bf16(sA[kt][4 * m + 0], sA[kt][4 * m + 1]);
          c1h[m] = cvtpk_bf16(sA[kt][4 * m + 2], sA[kt][4 * m + 3]);
        }
#pragma unroll
        for (int sI = 0; sI < 2; ++sI) {
          unsigned dw0, dw1, dw2, dw3;
          xsw<S2>(c0h[2 * sI], c0h[2 * sI + 1], dw0, dw2);
          xsw<S2>(c1h[2 * sI], c1h[2 * sI + 1], dw1, dw3);
          union U { uint4 u; short8 s8; } FH;
          FH.u = make_uint4(dw0, dw1, dw2, dw3);
          fragh[kt * 2 + sI] = FH.s8;
        }
      }
      __builtin_amdgcn_s_setprio(1);
#pragma unroll
      for (int ks = 0; ks < 4; ++ks) {
        short8 vf0 = *(const short8*)(cur + 16384 + va[ks]);
        short8 vf1 = *(const short8*)(cur + 16384 + 4096 + va[ks]);
        o[0] = MFMA32(vf0, fragh[ks], o[0]);
        o[1] = MFMA32(vf1, fragh[ks], o[1]);
        osum = MFMA32(ones, fragh[ks], osum);
      }
      __builtin_amdgcn_s_setprio(0);
    }

    // ---- softmax-B ----
#pragma unroll
    for (int kt = 0; kt < 2; ++kt)
#pragma unroll
      for (int m = 0; m < 4; ++m) {
        unsigned nib = ((unsigned)(mwB >> (kt * 32 + m * 8 + 4 * hi))) & 0xFu;
#pragma unroll
        for (int r = 0; r < 4; ++r)
          sB[kt][4 * m + r] = ((nib >> r) & 1u) ? -1e30f : sB[kt][4 * m + r];
      }
    float mxB = sB[0][0];
#pragma unroll
    for (int kt = 0; kt < 2; ++kt)
#pragma unroll
      for (int e = (kt == 0 ? 1 : 0); e < 16; ++e)
        mxB = fmaxf(mxB, sB[kt][e]);
    mxB = fmaxf(mxB, __shfl_xor(mxB, 32));
    const bool growB = __any(mxB > mrun + 11.0f);
    const float mnewB = growB ? fmaxf(mrun, mxB) : mrun;
#pragma unroll
    for (int kt = 0; kt < 2; ++kt)
#pragma unroll
      for (int e = 0; e < 16; ++e) sB[kt][e] = EXP2(sB[kt][e] - mnewB);
    if (growB) {
      float sc = EXP2(mrun - mnewB);
      mrun = mnewB;
      osum[0] *= sc;
#pragma unroll
      for (int dt = 0; dt < 2; ++dt)
#pragma unroll
        for (int e = 0; e < 16; ++e) o[dt][e] *= sc;
    }

    // ---- pack-B + PV-B ----
    {
      short8 fragh[4];
#pragma unroll
      for (int kt = 0; kt < 2; ++kt) {
        unsigned c0h[4], c1h[4];
#pragma unroll
        for (int m = 0; m < 4; ++m) {
          c0h[m] = cvtpk_bf16(sB[kt][4 * m + 0], sB[kt][4 * m + 1]);
          c1h[m] = cvtpk_bf16(sB[kt][4 * m + 2], sB[kt][4 * m + 3]);
        }
#pragma unroll
        for (int sI = 0; sI < 2; ++sI) {
          unsigned dw0, dw1, dw2, dw3;
          xsw<S2>(c0h[2 * sI], c0h[2 * sI + 1], dw0, dw2);
          xsw<S2>(c1h[2 * sI], c1h[2 * sI + 1], dw1, dw3);
          union U { uint4 u; short8 s8; } FH;
          FH.u = make_uint4(dw0, dw1, dw2, dw3);
          fragh[kt * 2 + sI] = FH.s8;
        }
      }
      __builtin_amdgcn_s_setprio(1);
#pragma unroll
      for (int ks = 0; ks < 4; ++ks) {
        short8 vf0 = *(const short8*)(cur + 24576 + va[ks]);
        short8 vf1 = *(const short8*)(cur + 24576 + 4096 + va[ks]);
        o[0] = MFMA32(vf0, fragh[ks], o[0]);
        o[1] = MFMA32(vf1, fragh[ks], o[1]);
        osum = MFMA32(ones, fragh[ks], osum);
      }
      __builtin_amdgcn_s_setprio(0);
    }

    __syncthreads();
  }

  const float lsum = osum[0];
  const float invl = lsum > 0.0f ? 1.0f / lsum : 0.0f;
#pragma unroll
  for (int dt = 0; dt < 2; ++dt)
#pragma unroll
    for (int m = 0; m < 4; ++m) {
      float4 v;
      v.x = o[dt][4 * m + 0] * invl;
      v.y = o[dt][4 * m + 1] * invl;
      v.z = o[dt][4 * m + 2] * invl;
      v.w = o[dt][4 * m + 3] * invl;
      const int d = dt * 32 + m * 8 + 4 * hi;
      *(float4*)&Ob[(size_t)qglob * 512 + d] = v;
    }
}

// ---------------- Kernel 2: flash attention ----------------
__global__ __launch_bounds__(256, 2) void attn_kernel(
    const unsigned short* __restrict__ Qh,
    const unsigned short* __restrict__ Kh, const unsigned short* __restrict__ Vh,
    const unsigned long long* __restrict__ Mp, float* __restrict__ out) {
  __shared__ __align__(16) unsigned short kvb[2][4][64][64];  // 64 KB double buffer

  const int hi = (threadIdx.x & 63) >> 5;
  unsigned ta = 1u + (unsigned)hi;
  unsigned tb = 3u + (unsigned)hi;
  permswap(ta, tb);
  const bool s2 = (__builtin_amdgcn_readfirstlane(ta) == 1u);

  if (s2) attn_body<true>(kvb, Qh, Kh, Vh, Mp, out);
  else    attn_body<false>(kvb, Qh, Kh, Vh, Mp, out);
}

extern "C" void kernel_launch(void* const* d_in, const int* in_sizes, int n_in,
                              void* d_out, int out_size, void* d_ws, size_t ws_size,
                              hipStream_t stream) {
  const float* x = (const float*)d_in[0];
  const void* mask = d_in[1];
  const float* Wq = (const float*)d_in[2];
  const float* Wk = (const float*)d_in[3];
  const float* Wv = (const float*)d_in[4];
  float* out = (float*)d_out;

  const size_t PLANE = (size_t)NBH * NSEQ * DH;  // 4,194,304 ushorts
  unsigned short* Qh = (unsigned short*)d_ws;
  unsigned short* Kh = Qh + PLANE;
  unsigned short* Vh = Kh + PLANE;
  unsigned short* xh = Vh + PLANE;
  unsigned short* wh = xh + PLANE;               // 3 * 262,144 ushorts
  unsigned short* wl = wh + 786432;
  unsigned long long* Mp = (unsigned long long*)(wl + 786432);  // 2 MB

  prep_kernel<<<1024, 256, 0, stream>>>(mask, Mp, x, Wq, Wk, Wv, xh, wh, wl);
  proj_kernel<<<dim3(128, 8), 256, 0, stream>>>(xh, wh, wl, Qh, Kh, Vh);
  attn_kernel<<<512, 256, 0, stream>>>(Qh, Kh, Vh, Mp, out);
}

// Round 20
// 104.381 us; speedup vs baseline: 1.6247x; 1.1155x over previous
//
#include <hip/hip_runtime.h>

// Attention_29231547416680: B=4, N=2048, CH=512, H=8, D=64, fp32 in/out.
// R20 = R19 with W single-bf16 (all tensors now single bf16; error budget:
//       measured 1.95e-3 with 2.9x headroom, W adds ~sqrt2x -> ~3e-3) and a
//       one-pass proj epilogue (6 barriers -> 2). proj: 4 staged tiles (16KB),
//       12 MFMA16/k-step. attn byte-identical to R19 (at its structural floor).

typedef float f32x4 __attribute__((ext_vector_type(4)));
typedef float f32x16 __attribute__((ext_vector_type(16)));
typedef short short8 __attribute__((ext_vector_type(8)));

#define MFMA16(a, b, c) __builtin_amdgcn_mfma_f32_16x16x32_bf16((a), (b), (c), 0, 0, 0)
#define MFMA32(a, b, c) __builtin_amdgcn_mfma_f32_32x32x16_bf16((a), (b), (c), 0, 0, 0)

#if __has_builtin(__builtin_amdgcn_exp2f)
#define EXP2(x) __builtin_amdgcn_exp2f(x)
#else
#define EXP2(x) exp2f(x)
#endif

#define NBH 32
#define NSEQ 2048
#define DH 64

__device__ __forceinline__ unsigned short f2bf(float f) {
  unsigned int u = __float_as_uint(f);
  u += 0x7fffu + ((u >> 16) & 1u);  // RTNE
  return (unsigned short)(u >> 16);
}

__device__ __forceinline__ unsigned cvtpk_bf16(float a, float b) {
  unsigned d;
  asm("v_cvt_pk_bf16_f32 %0, %1, %2" : "=v"(d) : "v"(a), "v"(b));
  return d;
}
__device__ __forceinline__ void permswap(unsigned& a, unsigned& b) {
  asm("v_permlane32_swap_b32 %0, %1" : "+v"(a), "+v"(b));
}
// lo = (ce.row0 | co.row0), hi = (ce.row1 | co.row1); S2 selects HW direction.
template <bool S2>
__device__ __forceinline__ void xsw(unsigned ce, unsigned co, unsigned& lo, unsigned& hi) {
  if (S2) { permswap(ce, co); }
  else    { permswap(co, ce); }
  lo = ce;
  hi = co;
}

// async global -> LDS, 16 bytes per lane; LDS dst = wave-uniform base + lane*16.
typedef __attribute__((address_space(1))) const unsigned int as1_u32;
typedef __attribute__((address_space(3))) unsigned int as3_u32;
__device__ __forceinline__ void gld_lds16(const unsigned short* g, unsigned short* l) {
  __builtin_amdgcn_global_load_lds((as1_u32*)g, (as3_u32*)l, 16, 0, 0);
}

// ---------------- prep: mask bit-pack + x/W bf16 convert ----------------
__global__ __launch_bounds__(256) void prep_kernel(
    const void* __restrict__ mraw, unsigned long long* __restrict__ Mp,
    const float* __restrict__ x,
    const float* __restrict__ Wq, const float* __restrict__ Wk, const float* __restrict__ Wv,
    unsigned short* __restrict__ xh, unsigned short* __restrict__ wh) {
  const int tid = threadIdx.x;
  __shared__ int s_bad;
  if (tid == 0) s_bad = 0;
  __syncthreads();
  const unsigned int* mw32 = (const unsigned int*)mraw;
  {
    unsigned int w0 = mw32[tid], w1 = mw32[256 + tid];
    bool ok = (w0 == 0u || w0 == 1u || w0 == 0x3f800000u) &&
              (w1 == 0u || w1 == 1u || w1 == 0x3f800000u);
    if (!ok) s_bad = 1;
  }
  __syncthreads();
  const size_t e0 = (size_t)blockIdx.x * 16384 + (size_t)tid * 64;
  unsigned long long bits = 0ull;
  if (s_bad == 0) {
    const uint4* p = (const uint4*)mw32 + (e0 >> 2);
#pragma unroll
    for (int j = 0; j < 16; ++j) {
      uint4 v = p[j];
      unsigned nib = (v.x != 0u) | ((v.y != 0u) << 1) | ((v.z != 0u) << 2) | ((v.w != 0u) << 3);
      bits |= (unsigned long long)nib << (j * 4);
    }
  } else {
    const uint4* p = (const uint4*)((const unsigned char*)mraw + e0);
#pragma unroll
    for (int j = 0; j < 4; ++j) {
      uint4 v = p[j];
      unsigned dw[4] = {v.x, v.y, v.z, v.w};
#pragma unroll
      for (int d = 0; d < 4; ++d) {
        unsigned nib = (((dw[d]) & 0xffu) != 0u) | ((((dw[d] >> 8) & 0xffu) != 0u) << 1) |
                       ((((dw[d] >> 16) & 0xffu) != 0u) << 2) | ((((dw[d] >> 24) & 0xffu) != 0u) << 3);
        bits |= (unsigned long long)nib << ((j * 4 + d) * 4);
      }
    }
  }
  Mp[e0 >> 6] = bits;

  const int gtid = blockIdx.x * 256 + tid;
  const float4* x4 = (const float4*)x;
#pragma unroll
  for (int rep = 0; rep < 4; ++rep) {
    int i = gtid + rep * 262144;
    float4 v = x4[i];
    *(ushort4*)&xh[(size_t)i * 4] =
        make_ushort4(f2bf(v.x), f2bf(v.y), f2bf(v.z), f2bf(v.w));
  }
  if (gtid < 65536) {
    const float* Ws[3] = {Wq, Wk, Wv};
#pragma unroll
    for (int z = 0; z < 3; ++z) {
      float4 v = ((const float4*)Ws[z])[gtid];
      size_t o = (size_t)z * 262144 + (size_t)gtid * 4;
      *(ushort4*)&wh[o] =
          make_ushort4(f2bf(v.x), f2bf(v.y), f2bf(v.z), f2bf(v.w));
    }
  }
}

// ---------------- Kernel 1: QKV projection (all single bf16; 4 tiles) ----------------
__global__ __launch_bounds__(256, 4) void proj_kernel(
    const unsigned short* __restrict__ xh, const unsigned short* __restrict__ wh,
    unsigned short* __restrict__ Qh, unsigned short* __restrict__ Kh,
    unsigned short* __restrict__ Vh) {
  const int tid = threadIdx.x;
  const int w = tid >> 6, l = tid & 63;
  const int m0 = blockIdx.x * 64;
  const int h = blockIdx.y;
  const int lrow = l & 15, lg = l >> 4;
  const int rw = (w >> 1) * 32, cw = (w & 1) * 32;

  union LDSU {
    unsigned short tiles[4][64][32];  // 16 KB staging: 0 xh, 1+z Wz
    unsigned short ob[3][64][72];     // 27.6 KB one-pass epilogue bounce
  };
  __shared__ __align__(16) LDSU u;

  f32x4 acc[3][2][2] = {};

  const unsigned short* planes[4] = {xh, wh, wh + 262144, wh + 524288};
  const int rowb[4] = {m0, h * 64, h * 64, h * 64};
  const int srow = l >> 2, scol = (l & 3) * 8;
  const unsigned short* s0 = planes[w] + (size_t)(rowb[w] + srow) * 512 + scol;
  unsigned short* d0 = &u.tiles[w][0][0];

  for (int k0 = 0; k0 < 512; k0 += 32) {
    __syncthreads();
#pragma unroll
    for (int c = 0; c < 4; ++c) gld_lds16(s0 + k0 + c * 8192, d0 + c * 512);
    __syncthreads();

    short8 axh[2];
#pragma unroll
    for (int t = 0; t < 2; ++t)
      axh[t] = *(const short8*)&u.tiles[0][rw + 16 * t + lrow][lg * 8];
#pragma unroll
    for (int z = 0; z < 3; ++z) {
      short8 bh[2];
#pragma unroll
      for (int t = 0; t < 2; ++t)
        bh[t] = *(const short8*)&u.tiles[1 + z][cw + 16 * t + lrow][lg * 8];
#pragma unroll
      for (int tm = 0; tm < 2; ++tm)
#pragma unroll
        for (int tn = 0; tn < 2; ++tn)
          acc[z][tm][tn] = MFMA16(axh[tm], bh[tn], acc[z][tm][tn]);
    }
  }

  // ---- one-pass epilogue ----
  const float qsc = 1.4426950408889634f * 0.08838834764831845f;  // log2e/sqrt(128)
  __syncthreads();  // staging reads done; tiles region reusable as ob
#pragma unroll
  for (int z = 0; z < 3; ++z)
#pragma unroll
    for (int tm = 0; tm < 2; ++tm)
#pragma unroll
      for (int tn = 0; tn < 2; ++tn) {
        int dcol = cw + tn * 16 + lrow;
        int nl = rw + tm * 16 + lg * 4;
#pragma unroll
        for (int r = 0; r < 4; ++r) {
          float v = acc[z][tm][tn][r];
          if (z == 0) v *= qsc;
          if (z < 2) u.ob[z][nl + r][dcol] = f2bf(v);
          else       u.ob[2][dcol][nl + r] = f2bf(v);  // V: transposed
        }
      }
  __syncthreads();
  {
    const int orow = tid >> 2, oc = (tid & 3) * 16;
    const int b = m0 >> 11, n0 = m0 & 2047, bhid = b * 8 + blockIdx.y;
    size_t base = ((size_t)bhid * 2048 + n0 + orow) * 64 + oc;
    *(short8*)&Qh[base] = *(const short8*)&u.ob[0][orow][oc];
    *(short8*)&Qh[base + 8] = *(const short8*)&u.ob[0][orow][oc + 8];
    *(short8*)&Kh[base] = *(const short8*)&u.ob[1][orow][oc];
    *(short8*)&Kh[base + 8] = *(const short8*)&u.ob[1][orow][oc + 8];
    size_t vb = ((size_t)bhid * 64 + orow) * 2048 + n0 + oc;
    *(short8*)&Vh[vb] = *(const short8*)&u.ob[2][orow][oc];
    *(short8*)&Vh[vb + 8] = *(const short8*)&u.ob[2][orow][oc + 8];
  }
}

// ---------------- attention body (R19 verbatim) ----------------
template <bool S2>
__device__ __forceinline__ void attn_body(
    unsigned short (&kvb)[2][4][64][64],
    const unsigned short* __restrict__ Qh,
    const unsigned short* __restrict__ Kh, const unsigned short* __restrict__ Vh,
    const unsigned long long* __restrict__ Mp, float* __restrict__ out) {
  const int tid = threadIdx.x;
  const int w = tid >> 6, l = tid & 63;
  const int wl = blockIdx.x;
  const int rm = (wl & 7) * 64 + (wl >> 3);  // XCD swizzle (512 = 8*64, bijective)
  const int q0 = (rm & 15) * 128;
  const int bh = rm >> 4;
  const int b = bh >> 3, h = bh & 7;
  const int l31 = l & 31, hi = l >> 5;
  const int swz = (l31 & 7) << 4;

  const unsigned short* Qhb = Qh + (size_t)bh * NSEQ * DH;
  const unsigned short* Khb = Kh + (size_t)bh * NSEQ * DH;
  const unsigned short* Vhb = Vh + (size_t)bh * DH * NSEQ;
  const unsigned long long* Mb = Mp + (size_t)b * NSEQ * 32;
  float* Ob = out + (size_t)b * NSEQ * 512 + h * 64;

  char* kv0 = (char*)&kvb[0][0][0][0];

  int va[4];
#pragma unroll
  for (int d = 0; d < 4; ++d) va[d] = l31 * 128 + (((d * 32) | (hi * 16)) ^ swz);

  const size_t qoff = (size_t)(q0 + w * 32 + l31) * 64 + hi * 8;
  short8 qh[4];
#pragma unroll
  for (int d = 0; d < 4; ++d) qh[d] = *(const short8*)(Qhb + qoff + d * 16);

  short8 ones;
#pragma unroll
  for (int j = 0; j < 8; ++j) ones[j] = (short)0x3F80;

  f32x16 o[2] = {};
  f32x16 osum = {};
  float mrun = -1e30f;
  const int qglob = q0 + w * 32 + l31;

  const int row0 = tid >> 3, colx = (tid & 7) * 8;
  const int swst = (colx * 2) ^ ((row0 & 7) << 4);
  int dstK[4], dstV[4];
#pragma unroll
  for (int c = 0; c < 4; ++c) {
    const int rsub = (c & 1) * 32 + row0;
    dstK[c] = (c >> 1) * 8192 + rsub * 128 + swst;
    dstV[c] = 16384 + (c >> 1) * 8192 + rsub * 128 + swst;
  }
  size_t koff[4], voff[4];
#pragma unroll
  for (int c = 0; c < 4; ++c) {
    koff[c] = (size_t)(c * 32 + row0) * 64 + colx;
    voff[c] = (size_t)((c & 1) * 32 + row0) * 2048 + (c >> 1) * 64 + colx;
  }

  short8 sk[4], sv[4];
#pragma unroll
  for (int c = 0; c < 4; ++c) {
    sk[c] = *(const short8*)(Khb + koff[c]);
    sv[c] = *(const short8*)(Vhb + voff[c]);
  }
#pragma unroll
  for (int c = 0; c < 4; ++c) {
    *(short8*)(kv0 + dstK[c]) = sk[c];
    *(short8*)(kv0 + dstV[c]) = sv[c];
  }
#pragma unroll
  for (int c = 0; c < 4; ++c) {
    koff[c] += 8192; voff[c] += 128;
    sk[c] = *(const short8*)(Khb + koff[c]);
    sv[c] = *(const short8*)(Vhb + voff[c]);
  }
  __syncthreads();

  for (int it = 0; it < 16; ++it) {
    char* cur = kv0 + (size_t)(it & 1) * 32768;
    if (it < 15) {
      char* nb = kv0 + (size_t)((it + 1) & 1) * 32768;
#pragma unroll
      for (int c = 0; c < 4; ++c) {
        *(short8*)(nb + dstK[c]) = sk[c];
        *(short8*)(nb + dstV[c]) = sv[c];
      }
      if (it < 14) {
#pragma unroll
        for (int c = 0; c < 4; ++c) {
          koff[c] += 8192; voff[c] += 128;
          sk[c] = *(const short8*)(Khb + koff[c]);
          sv[c] = *(const short8*)(Vhb + voff[c]);
        }
      }
    }

    const unsigned long long mwA = Mb[(size_t)qglob * 32 + 2 * it];
    const unsigned long long mwB = Mb[(size_t)qglob * 32 + 2 * it + 1];

    f32x16 sA[2] = {}, sB[2] = {};
    __builtin_amdgcn_s_setprio(1);
#pragma unroll
    for (int d = 0; d < 4; ++d)
#pragma unroll
      for (int kt = 0; kt < 2; ++kt) {
        short8 kfa = *(const short8*)(cur + kt * 4096 + va[d]);
        sA[kt] = MFMA32(kfa, qh[d], sA[kt]);
      }
#pragma unroll
    for (int d = 0; d < 4; ++d)
#pragma unroll
      for (int kt = 0; kt < 2; ++kt) {
        short8 kfb = *(const short8*)(cur + 8192 + kt * 4096 + va[d]);
        sB[kt] = MFMA32(kfb, qh[d], sB[kt]);
      }
    __builtin_amdgcn_s_setprio(0);

    // ---- softmax-A ----
#pragma unroll
    for (int kt = 0; kt < 2; ++kt)
#pragma unroll
      for (int m = 0; m < 4; ++m) {
        unsigned nib = ((unsigned)(mwA >> (kt * 32 + m * 8 + 4 * hi))) & 0xFu;
#pragma unroll
        for (int r = 0; r < 4; ++r)
          sA[kt][4 * m + r] = ((nib >> r) & 1u) ? -1e30f : sA[kt][4 * m + r];
      }
    float mxA = sA[0][0];
#pragma unroll
    for (int kt = 0; kt < 2; ++kt)
#pragma unroll
      for (int e = (kt == 0 ? 1 : 0); e < 16; ++e)
        mxA = fmaxf(mxA, sA[kt][e]);
    mxA = fmaxf(mxA, __shfl_xor(mxA, 32));
    const bool growA = __any(mxA > mrun + 11.0f);
    const float mnewA = growA ? fmaxf(mrun, mxA) : mrun;
#pragma unroll
    for (int kt = 0; kt < 2; ++kt)
#pragma unroll
      for (int e = 0; e < 16; ++e) sA[kt][e] = EXP2(sA[kt][e] - mnewA);
    if (growA) {
      float sc = EXP2(mrun - mnewA);
      mrun = mnewA;
      osum[0] *= sc;
#pragma unroll
      for (int dt = 0; dt < 2; ++dt)
#pragma unroll
        for (int e = 0; e < 16; ++e) o[dt][e] *= sc;
    }

    // ---- pack-A + PV-A ----
    {
      short8 fragh[4];
#pragma unroll
      for (int kt = 0; kt < 2; ++kt) {
        unsigned c0h[4], c1h[4];
#pragma unroll
        for (int m = 0; m < 4; ++m) {
          c0h[m] = cvtpk_bf16(sA[kt][4 * m + 0], sA[kt][4 * m + 1]);
          c1h[m] = cvtpk_bf16(sA[kt][4 * m + 2], sA[kt][4 * m + 3]);
        }
#pragma unroll
        for (int sI = 0; sI < 2; ++sI) {
          unsigned dw0, dw1, dw2, dw3;
          xsw<S2>(c0h[2 * sI], c0h[2 * sI + 1], dw0, dw2);
          xsw<S2>(c1h[2 * sI], c1h[2 * sI + 1], dw1, dw3);
          union U { uint4 u; short8 s8; } FH;
          FH.u = make_uint4(dw0, dw1, dw2, dw3);
          fragh[kt * 2 + sI] = FH.s8;
        }
      }
      __builtin_amdgcn_s_setprio(1);
#pragma unroll
      for (int ks = 0; ks < 4; ++ks) {
        short8 vf0 = *(const short8*)(cur + 16384 + va[ks]);
        short8 vf1 = *(const short8*)(cur + 16384 + 4096 + va[ks]);
        o[0] = MFMA32(vf0, fragh[ks], o[0]);
        o[1] = MFMA32(vf1, fragh[ks], o[1]);
        osum = MFMA32(ones, fragh[ks], osum);
      }
      __builtin_amdgcn_s_setprio(0);
    }

    // ---- softmax-B ----
#pragma unroll
    for (int kt = 0; kt < 2; ++kt)
#pragma unroll
      for (int m = 0; m < 4; ++m) {
        unsigned nib = ((unsigned)(mwB >> (kt * 32 + m * 8 + 4 * hi))) & 0xFu;
#pragma unroll
        for (int r = 0; r < 4; ++r)
          sB[kt][4 * m + r] = ((nib >> r) & 1u) ? -1e30f : sB[kt][4 * m + r];
      }
    float mxB = sB[0][0];
#pragma unroll
    for (int kt = 0; kt < 2; ++kt)
#pragma unroll
      for (int e = (kt == 0 ? 1 : 0); e < 16; ++e)
        mxB = fmaxf(mxB, sB[kt][e]);
    mxB = fmaxf(mxB, __shfl_xor(mxB, 32));
    const bool growB = __any(mxB > mrun + 11.0f);
    const float mnewB = growB ? fmaxf(mrun, mxB) : mrun;
#pragma unroll
    for (int kt = 0; kt < 2; ++kt)
#pragma unroll
      for (int e = 0; e < 16; ++e) sB[kt][e] = EXP2(sB[kt][e] - mnewB);
    if (growB) {
      float sc = EXP2(mrun - mnewB);
      mrun = mnewB;
      osum[0] *= sc;
#pragma unroll
      for (int dt = 0; dt < 2; ++dt)
#pragma unroll
        for (int e = 0; e < 16; ++e) o[dt][e] *= sc;
    }

    // ---- pack-B + PV-B ----
    {
      short8 fragh[4];
#pragma unroll
      for (int kt = 0; kt < 2; ++kt) {
        unsigned c0h[4], c1h[4];
#pragma unroll
        for (int m = 0; m < 4; ++m) {
          c0h[m] = cvtpk_bf16(sB[kt][4 * m + 0], sB[kt][4 * m + 1]);
          c1h[m] = cvtpk_bf16(sB[kt][4 * m + 2], sB[kt][4 * m + 3]);
        }
#pragma unroll
        for (int sI = 0; sI < 2; ++sI) {
          unsigned dw0, dw1, dw2, dw3;
          xsw<S2>(c0h[2 * sI], c0h[2 * sI + 1], dw0, dw2);
          xsw<S2>(c1h[2 * sI], c1h[2 * sI + 1], dw1, dw3);
          union U { uint4 u; short8 s8; } FH;
          FH.u = make_uint4(dw0, dw1, dw2, dw3);
          fragh[kt * 2 + sI] = FH.s8;
        }
      }
      __builtin_amdgcn_s_setprio(1);
#pragma unroll
      for (int ks = 0; ks < 4; ++ks) {
        short8 vf0 = *(const short8*)(cur + 24576 + va[ks]);
        short8 vf1 = *(const short8*)(cur + 24576 + 4096 + va[ks]);
        o[0] = MFMA32(vf0, fragh[ks], o[0]);
        o[1] = MFMA32(vf1, fragh[ks], o[1]);
        osum = MFMA32(ones, fragh[ks], osum);
      }
      __builtin_amdgcn_s_setprio(0);
    }

    __syncthreads();
  }

  const float lsum = osum[0];
  const float invl = lsum > 0.0f ? 1.0f / lsum : 0.0f;
#pragma unroll
  for (int dt = 0; dt < 2; ++dt)
#pragma unroll
    for (int m = 0; m < 4; ++m) {
      float4 v;
      v.x = o[dt][4 * m + 0] * invl;
      v.y = o[dt][4 * m + 1] * invl;
      v.z = o[dt][4 * m + 2] * invl;
      v.w = o[dt][4 * m + 3] * invl;
      const int d = dt * 32 + m * 8 + 4 * hi;
      *(float4*)&Ob[(size_t)qglob * 512 + d] = v;
    }
}

// ---------------- Kernel 2: flash attention ----------------
__global__ __launch_bounds__(256, 2) void attn_kernel(
    const unsigned short* __restrict__ Qh,
    const unsigned short* __restrict__ Kh, const unsigned short* __restrict__ Vh,
    const unsigned long long* __restrict__ Mp, float* __restrict__ out) {
  __shared__ __align__(16) unsigned short kvb[2][4][64][64];  // 64 KB double buffer

  const int hi = (threadIdx.x & 63) >> 5;
  unsigned ta = 1u + (unsigned)hi;
  unsigned tb = 3u + (unsigned)hi;
  permswap(ta, tb);
  const bool s2 = (__builtin_amdgcn_readfirstlane(ta) == 1u);

  if (s2) attn_body<true>(kvb, Qh, Kh, Vh, Mp, out);
  else    attn_body<false>(kvb, Qh, Kh, Vh, Mp, out);
}

extern "C" void kernel_launch(void* const* d_in, const int* in_sizes, int n_in,
                              void* d_out, int out_size, void* d_ws, size_t ws_size,
                              hipStream_t stream) {
  const float* x = (const float*)d_in[0];
  const void* mask = d_in[1];
  const float* Wq = (const float*)d_in[2];
  const float* Wk = (const float*)d_in[3];
  const float* Wv = (const float*)d_in[4];
  float* out = (float*)d_out;

  const size_t PLANE = (size_t)NBH * NSEQ * DH;  // 4,194,304 ushorts
  unsigned short* Qh = (unsigned short*)d_ws;
  unsigned short* Kh = Qh + PLANE;
  unsigned short* Vh = Kh + PLANE;
  unsigned short* xh = Vh + PLANE;
  unsigned short* wh = xh + PLANE;               // 3 * 262,144 ushorts
  unsigned long long* Mp = (unsigned long long*)(wh + 786432);  // 2 MB

  prep_kernel<<<1024, 256, 0, stream>>>(mask, Mp, x, Wq, Wk, Wv, xh, wh);
  proj_kernel<<<dim3(128, 8), 256, 0, stream>>>(xh, wh, Qh, Kh, Vh);
  attn_kernel<<<512, 256, 0, stream>>>(Qh, Kh, Vh, Mp, out);
}